// Round 7
// baseline (322.697 us; speedup 1.0000x reference)
//
#include <hip/hip_runtime.h>
#include <hip/hip_bf16.h>

#define EMB 512
#define HEADS 8
#define KD 64
#define SEQ 2048
#define BATCH 4

typedef __attribute__((ext_vector_type(8))) short bf16x8;
typedef __attribute__((ext_vector_type(4))) float f32x4;

__device__ __forceinline__ unsigned short f2bf(float x) {
    union { float f; unsigned u; } v; v.f = x;
    unsigned r = v.u + 0x7fff + ((v.u >> 16) & 1);   // RNE
    return (unsigned short)(r >> 16);
}
__device__ __forceinline__ float bf2f(unsigned short b) {
    union { unsigned u; float f; } v; v.u = ((unsigned)b) << 16;
    return v.f;
}

// ---------------------------------------------------------------------------
// Prep: K fp32 -> per-(bh,tile) images [hi 64x64][lo 64x64] bf16 (contiguous)
// K tile (bh,t) is already a contiguous 4096-float block of [B,H,S,64].
// ---------------------------------------------------------------------------
__global__ __launch_bounds__(256) void prep_k_kernel(const float* __restrict__ K,
                                                     unsigned short* __restrict__ kimg) {
    const int bt = blockIdx.x;                       // bh*32 + tile, 0..1023
    const float4* src = (const float4*)(K + (size_t)bt * 4096);
    unsigned short* dhi = kimg + (size_t)bt * 8192;
    unsigned short* dlo = dhi + 4096;
#pragma unroll
    for (int it = 0; it < 4; ++it) {
        const int idx = threadIdx.x + it * 256;      // 0..1023 float4s
        const float4 v = src[idx];
        const unsigned short h0 = f2bf(v.x), h1 = f2bf(v.y),
                             h2 = f2bf(v.z), h3 = f2bf(v.w);
        *(uint2*)&dhi[idx * 4] = make_uint2(
            (unsigned)h0 | ((unsigned)h1 << 16),
            (unsigned)h2 | ((unsigned)h3 << 16));
        *(uint2*)&dlo[idx * 4] = make_uint2(
            (unsigned)f2bf(v.x - bf2f(h0)) | ((unsigned)f2bf(v.y - bf2f(h1)) << 16),
            (unsigned)f2bf(v.z - bf2f(h2)) | ((unsigned)f2bf(v.w - bf2f(h3)) << 16));
    }
}

// ---------------------------------------------------------------------------
// Prep: V fp32 -> per-(bh,tile) transposed images [d 64][s 64] bf16
// ---------------------------------------------------------------------------
__global__ __launch_bounds__(256) void prep_v_kernel(const float* __restrict__ V,
                                                     unsigned short* __restrict__ vimg) {
    const int bt = blockIdx.x;
    const float* src = V + (size_t)bt * 4096;
    unsigned short* dst = vimg + (size_t)bt * 4096;
#pragma unroll
    for (int it = 0; it < 2; ++it) {
        const int idx = threadIdx.x + it * 256;      // 0..511
        const int sp  = idx & 31;                    // s-pair
        const int d4  = (idx >> 5) << 2;
        const float4 a = *(const float4*)(src + (2 * sp) * KD + d4);
        const float4 b = *(const float4*)(src + (2 * sp + 1) * KD + d4);
#pragma unroll
        for (int j = 0; j < 4; ++j) {
            const float aj = (&a.x)[j], bj = (&b.x)[j];
            *(unsigned*)&dst[(d4 + j) * 64 + 2 * sp] =
                (unsigned)f2bf(aj) | ((unsigned)f2bf(bj) << 16);
        }
    }
}

// ---------------------------------------------------------------------------
// MFMA flash attention, QB=128 (2 q-subtiles/wave), split-bf16 QK^T.
// PREP=1: K/V staged by pure uint4 copy from pre-converted images.
// PREP=0: in-kernel fp32->bf16 conversion staging (ws-too-small fallback).
// ---------------------------------------------------------------------------
template <int PREP>
__global__ __launch_bounds__(256, 4) void attn2_kernel(const float* __restrict__ Q,
                                                       const float* __restrict__ Keys,
                                                       const float* __restrict__ Vals,
                                                       const unsigned short* __restrict__ kimg,
                                                       const unsigned short* __restrict__ vimg,
                                                       float* __restrict__ out) {
    constexpr int NT  = 64;
    constexpr int LDK = 72;

    __shared__ unsigned short k_s[2][NT][LDK];
    __shared__ unsigned short v_t[KD][LDK];
    __shared__ unsigned short p_s[4][16][LDK];

    const int t  = threadIdx.x;
    const int w  = t >> 6;
    const int l  = t & 63;
    const int g  = l >> 4;
    const int ln = l & 15;

    const int bh = blockIdx.y;
    const int q0 = blockIdx.x * 128;

    const float* kbase = Keys + (size_t)bh * SEQ * KD;
    const float* vbase = Vals + (size_t)bh * SEQ * KD;

    // Q fragments for both subtiles, hi+lo, pre-scaled 1/8
    bf16x8 qhi[2][2], qlo[2][2];
#pragma unroll
    for (int u = 0; u < 2; ++u) {
        const float* qptr = Q + ((size_t)bh * SEQ + q0 + u * 64 + w * 16 + ln) * KD;
#pragma unroll
        for (int kk = 0; kk < 2; ++kk) {
            const float* p = qptr + g * 8 + 32 * kk;
#pragma unroll
            for (int j = 0; j < 8; ++j) {
                const float x = p[j] * 0.125f;
                const unsigned short h = f2bf(x);
                qhi[u][kk][j] = (short)h;
                qlo[u][kk][j] = (short)f2bf(x - bf2f(h));
            }
        }
    }

    f32x4 acc[2][4];
#pragma unroll
    for (int u = 0; u < 2; ++u)
#pragma unroll
        for (int db = 0; db < 4; ++db) acc[u][db] = (f32x4){0.f, 0.f, 0.f, 0.f};
    float m_run[2] = {-1e30f, -1e30f};
    float l_run[2] = {0.f, 0.f};

    for (int tile = 0; tile < SEQ / NT; ++tile) {
        __syncthreads();

        if (PREP) {
            // ---- pure-copy staging from images ----
            const uint4* ksrc = (const uint4*)(kimg + (size_t)(bh * 32 + tile) * 8192);
#pragma unroll
            for (int it = 0; it < 4; ++it) {
                const int idx = t + it * 256;            // 0..1023 uint4s
                const int hl  = idx >> 9;
                const int rem = idx & 511;
                *(uint4*)&k_s[hl][rem >> 3][(rem & 7) * 8] = ksrc[idx];
            }
            const uint4* vsrc = (const uint4*)(vimg + (size_t)(bh * 32 + tile) * 4096);
#pragma unroll
            for (int it = 0; it < 2; ++it) {
                const int idx = t + it * 256;            // 0..511 uint4s
                *(uint4*)&v_t[idx >> 3][(idx & 7) * 8] = vsrc[idx];
            }
        } else {
            // ---- conversion staging (fallback) ----
            const float* kt = kbase + (size_t)tile * NT * KD;
            const float* vt = vbase + (size_t)tile * NT * KD;
#pragma unroll
            for (int it = 0; it < 4; ++it) {
                const int idx = t + it * 256;
                const int s   = idx >> 4;
                const int d4  = (idx & 15) << 2;
                const float4 kv = *(const float4*)(kt + s * KD + d4);
                unsigned short h0 = f2bf(kv.x), h1 = f2bf(kv.y),
                               h2 = f2bf(kv.z), h3 = f2bf(kv.w);
                *(uint2*)&k_s[0][s][d4] = make_uint2(
                    (unsigned)h0 | ((unsigned)h1 << 16),
                    (unsigned)h2 | ((unsigned)h3 << 16));
                *(uint2*)&k_s[1][s][d4] = make_uint2(
                    (unsigned)f2bf(kv.x - bf2f(h0)) | ((unsigned)f2bf(kv.y - bf2f(h1)) << 16),
                    (unsigned)f2bf(kv.z - bf2f(h2)) | ((unsigned)f2bf(kv.w - bf2f(h3)) << 16));
            }
#pragma unroll
            for (int it = 0; it < 2; ++it) {
                const int idx = t + it * 256;
                const int sp  = idx & 31;
                const int d4  = (idx >> 5) << 2;
                const float* v0 = vt + (2 * sp) * KD + d4;
                const float4 a = *(const float4*)v0;
                const float4 b = *(const float4*)(v0 + KD);
#pragma unroll
                for (int j = 0; j < 4; ++j) {
                    const float aj = (&a.x)[j], bj = (&b.x)[j];
                    *(unsigned*)&v_t[d4 + j][2 * sp] =
                        (unsigned)f2bf(aj) | ((unsigned)f2bf(bj) << 16);
                }
            }
        }
        __syncthreads();

#pragma unroll
        for (int u = 0; u < 2; ++u) {
            // ---- S^T = K·Q^T, 3-term split-bf16 ----
            f32x4 st[4];
#pragma unroll
            for (int sb = 0; sb < 4; ++sb) {
                f32x4 c = (f32x4){0.f, 0.f, 0.f, 0.f};
#pragma unroll
                for (int kk = 0; kk < 2; ++kk) {
                    const bf16x8 khi = *(const bf16x8*)&k_s[0][sb * 16 + ln][g * 8 + 32 * kk];
                    const bf16x8 klo = *(const bf16x8*)&k_s[1][sb * 16 + ln][g * 8 + 32 * kk];
                    c = __builtin_amdgcn_mfma_f32_16x16x32_bf16(klo, qhi[u][kk], c, 0, 0, 0);
                    c = __builtin_amdgcn_mfma_f32_16x16x32_bf16(khi, qlo[u][kk], c, 0, 0, 0);
                    c = __builtin_amdgcn_mfma_f32_16x16x32_bf16(khi, qhi[u][kk], c, 0, 0, 0);
                }
                st[sb] = c;
            }

            // ---- online softmax (q = ln within 16-lane group) ----
            float tm = st[0][0];
#pragma unroll
            for (int sb = 0; sb < 4; ++sb)
#pragma unroll
                for (int r = 0; r < 4; ++r) tm = fmaxf(tm, st[sb][r]);
            tm = fmaxf(tm, __shfl_xor(tm, 16));
            tm = fmaxf(tm, __shfl_xor(tm, 32));

            const float m_new  = fmaxf(m_run[u], tm);
            const float scalef = __expf(m_run[u] - m_new);
            m_run[u] = m_new;

            float rs = 0.f;
#pragma unroll
            for (int sb = 0; sb < 4; ++sb) {
                const float p0 = __expf(st[sb][0] - m_new);
                const float p1 = __expf(st[sb][1] - m_new);
                const float p2 = __expf(st[sb][2] - m_new);
                const float p3 = __expf(st[sb][3] - m_new);
                rs += (p0 + p1) + (p2 + p3);
                const unsigned lo = (unsigned)f2bf(p0) | ((unsigned)f2bf(p1) << 16);
                const unsigned hi = (unsigned)f2bf(p2) | ((unsigned)f2bf(p3) << 16);
                *(uint2*)&p_s[w][ln][sb * 16 + g * 4] = make_uint2(lo, hi);
            }
            rs += __shfl_xor(rs, 16);
            rs += __shfl_xor(rs, 32);
            l_run[u] = l_run[u] * scalef + rs;

#pragma unroll
            for (int r = 0; r < 4; ++r) {
                const float sr = __shfl(scalef, 4 * g + r);
#pragma unroll
                for (int db = 0; db < 4; ++db) acc[u][db][r] *= sr;
            }

            // ---- PV (p_s is per-wave; same-wave write->read, no barrier) ----
            bf16x8 pa[2];
#pragma unroll
            for (int kk = 0; kk < 2; ++kk)
                pa[kk] = *(const bf16x8*)&p_s[w][ln][g * 8 + 32 * kk];
#pragma unroll
            for (int db = 0; db < 4; ++db) {
                f32x4 c = acc[u][db];
#pragma unroll
                for (int kk = 0; kk < 2; ++kk) {
                    const bf16x8 vb = *(const bf16x8*)&v_t[ln + 16 * db][g * 8 + 32 * kk];
                    c = __builtin_amdgcn_mfma_f32_16x16x32_bf16(pa[kk], vb, c, 0, 0, 0);
                }
                acc[u][db] = c;
            }
        }
    }

    // ---- epilogue ----
    const int b = bh >> 3, h = bh & 7;
#pragma unroll
    for (int u = 0; u < 2; ++u) {
        const float invl = 1.0f / l_run[u];
#pragma unroll
        for (int r = 0; r < 4; ++r) {
            const float iv = __shfl(invl, 4 * g + r);
            float* orow = out + ((size_t)(b * SEQ + q0 + u * 64 + w * 16 + 4 * g + r) * EMB)
                          + h * KD + ln;
#pragma unroll
            for (int db = 0; db < 4; ++db) orow[16 * db] = acc[u][db][r] * iv;
        }
    }
}

// ---------------------------------------------------------------------------
// MFMA projection GEMM, split-bf16 (3-term). Tile 64x64, BK=64, 4 waves.
// TRANSQ=1: scatter output to [B,H,S,64]. NOT in-place safe.
// ---------------------------------------------------------------------------
template <int TRANSQ>
__global__ __launch_bounds__(256) void proj_mfma_kernel(const float* __restrict__ in,
                                                        const float* __restrict__ W,
                                                        float* __restrict__ out) {
    __shared__ unsigned short x_s[2][64][72];
    __shared__ unsigned short w_t[2][64][72];

    const int t  = threadIdx.x;
    const int w  = t >> 6;
    const int l  = t & 63;
    const int g  = l >> 4;
    const int ln = l & 15;

    const int row0 = blockIdx.x * 64;
    const int n0   = blockIdx.y * 64;

    f32x4 acc[4];
#pragma unroll
    for (int cb = 0; cb < 4; ++cb) acc[cb] = (f32x4){0.f, 0.f, 0.f, 0.f};

    for (int ch = 0; ch < EMB / 64; ++ch) {
        __syncthreads();
#pragma unroll
        for (int it = 0; it < 4; ++it) {
            const int idx = t + it * 256;
            const int s   = idx >> 4;
            const int d4  = (idx & 15) << 2;
            const float4 xv = *(const float4*)(in + (size_t)(row0 + s) * EMB + ch * 64 + d4);
            const unsigned short h0 = f2bf(xv.x), h1 = f2bf(xv.y),
                                 h2 = f2bf(xv.z), h3 = f2bf(xv.w);
            *(uint2*)&x_s[0][s][d4] = make_uint2(
                (unsigned)h0 | ((unsigned)h1 << 16),
                (unsigned)h2 | ((unsigned)h3 << 16));
            *(uint2*)&x_s[1][s][d4] = make_uint2(
                (unsigned)f2bf(xv.x - bf2f(h0)) | ((unsigned)f2bf(xv.y - bf2f(h1)) << 16),
                (unsigned)f2bf(xv.z - bf2f(h2)) | ((unsigned)f2bf(xv.w - bf2f(h3)) << 16));
        }
#pragma unroll
        for (int it = 0; it < 2; ++it) {
            const int idx = t + it * 256;
            const int sp  = idx & 31;
            const int c4  = (idx >> 5) << 2;
            const float* wrow = W + (size_t)(ch * 64 + 2 * sp) * EMB + n0 + c4;
            const float4 a = *(const float4*)wrow;
            const float4 b = *(const float4*)(wrow + EMB);
#pragma unroll
            for (int j = 0; j < 4; ++j) {
                const float aj = (&a.x)[j], bj = (&b.x)[j];
                const unsigned short ah = f2bf(aj), bh = f2bf(bj);
                *(unsigned*)&w_t[0][c4 + j][2 * sp] =
                    (unsigned)ah | ((unsigned)bh << 16);
                *(unsigned*)&w_t[1][c4 + j][2 * sp] =
                    (unsigned)f2bf(aj - bf2f(ah)) | ((unsigned)f2bf(bj - bf2f(bh)) << 16);
            }
        }
        __syncthreads();

        bf16x8 ah[2], al[2];
#pragma unroll
        for (int kk = 0; kk < 2; ++kk) {
            ah[kk] = *(const bf16x8*)&x_s[0][w * 16 + ln][g * 8 + 32 * kk];
            al[kk] = *(const bf16x8*)&x_s[1][w * 16 + ln][g * 8 + 32 * kk];
        }
#pragma unroll
        for (int cb = 0; cb < 4; ++cb) {
            f32x4 c = acc[cb];
#pragma unroll
            for (int kk = 0; kk < 2; ++kk) {
                const bf16x8 bh = *(const bf16x8*)&w_t[0][cb * 16 + ln][g * 8 + 32 * kk];
                const bf16x8 bl = *(const bf16x8*)&w_t[1][cb * 16 + ln][g * 8 + 32 * kk];
                c = __builtin_amdgcn_mfma_f32_16x16x32_bf16(al[kk], bh, c, 0, 0, 0);
                c = __builtin_amdgcn_mfma_f32_16x16x32_bf16(ah[kk], bl, c, 0, 0, 0);
                c = __builtin_amdgcn_mfma_f32_16x16x32_bf16(ah[kk], bh, c, 0, 0, 0);
            }
            acc[cb] = c;
        }
    }

#pragma unroll
    for (int cb = 0; cb < 4; ++cb) {
#pragma unroll
        for (int r = 0; r < 4; ++r) {
            const int row = row0 + w * 16 + 4 * g + r;
            const int col = n0 + cb * 16 + ln;
            if (TRANSQ) {
                const int b = row >> 11, s = row & 2047;
                const int h = col >> 6, k = col & 63;
                out[((size_t)(b * HEADS + h) * SEQ + s) * KD + k] = acc[cb][r];
            } else {
                out[(size_t)row * EMB + col] = acc[cb][r];
            }
        }
    }
}

// ---------------------------------------------------------------------------
// fp32 out-projection fallback (in-place safe: 8 rows fully staged first)
// ---------------------------------------------------------------------------
__global__ __launch_bounds__(256) void proj_fp32_kernel(const float* __restrict__ in,
                                                        const float* __restrict__ W,
                                                        float* __restrict__ out) {
    __shared__ float x_s[8][EMB];
    const int block_row = blockIdx.x * 8;

    const float4* in4 = (const float4*)(in + (size_t)block_row * EMB);
    float4* xs4 = (float4*)(&x_s[0][0]);
    for (int i = threadIdx.x; i < 8 * EMB / 4; i += 256) xs4[i] = in4[i];
    __syncthreads();

    const int n  = (threadIdx.x & 127) * 4;
    const int rg = threadIdx.x >> 7;

    float acc[4][4] = {};
    for (int e = 0; e < EMB; ++e) {
        const float4 w4 = *(const float4*)(W + (size_t)e * EMB + n);
#pragma unroll
        for (int rr = 0; rr < 4; ++rr) {
            const float xv = x_s[rg + rr * 2][e];
            acc[rr][0] += xv * w4.x;
            acc[rr][1] += xv * w4.y;
            acc[rr][2] += xv * w4.z;
            acc[rr][3] += xv * w4.w;
        }
    }
#pragma unroll
    for (int rr = 0; rr < 4; ++rr) {
        const int row = block_row + rg + rr * 2;
        float4 o;
        o.x = acc[rr][0]; o.y = acc[rr][1]; o.z = acc[rr][2]; o.w = acc[rr][3];
        *(float4*)(out + (size_t)row * EMB + n) = o;
    }
}

// ---------------------------------------------------------------------------
extern "C" void kernel_launch(void* const* d_in, const int* in_sizes, int n_in,
                              void* d_out, int out_size, void* d_ws, size_t ws_size,
                              hipStream_t stream) {
    const float* x  = (const float*)d_in[0];
    const float* ks = (const float*)d_in[1];
    const float* vs = (const float*)d_in[2];
    const float* wq = (const float*)d_in[3];
    const float* wo = (const float*)d_in[4];
    float* out = (float*)d_out;

    const size_t QBYTES = (size_t)BATCH * HEADS * SEQ * KD * 4;  // 16.8 MB
    const size_t CBYTES = (size_t)BATCH * SEQ * EMB * 4;         // 16.8 MB
    const size_t KIBYTES = (size_t)BATCH * HEADS * SEQ * KD * 2 * 2;  // hi+lo, 16.8 MB
    const size_t VIBYTES = (size_t)BATCH * HEADS * SEQ * KD * 2;      // 8.4 MB

    float* Q = (float*)d_ws;
    const bool mid_ws  = ws_size >= QBYTES + CBYTES;
    const bool full_ws = ws_size >= QBYTES + CBYTES + KIBYTES + VIBYTES;
    float* ctx = mid_ws ? (float*)((char*)d_ws + QBYTES) : out;
    unsigned short* kimg = (unsigned short*)((char*)d_ws + QBYTES + CBYTES);
    unsigned short* vimg = (unsigned short*)((char*)d_ws + QBYTES + CBYTES + KIBYTES);

    const int M = BATCH * SEQ;  // 8192

    // 1) Q = x @ Wq (MFMA split-bf16), scattered to [B,H,S,64]
    proj_mfma_kernel<1><<<dim3(M / 64, EMB / 64), dim3(256), 0, stream>>>(x, wq, Q);

    // 2) flash attention
    if (full_ws) {
        prep_k_kernel<<<dim3(BATCH * HEADS * 32), dim3(256), 0, stream>>>(ks, kimg);
        prep_v_kernel<<<dim3(BATCH * HEADS * 32), dim3(256), 0, stream>>>(vs, vimg);
        attn2_kernel<1><<<dim3(SEQ / 128, BATCH * HEADS), dim3(256), 0, stream>>>(
            Q, ks, vs, kimg, vimg, ctx);
    } else {
        attn2_kernel<0><<<dim3(SEQ / 128, BATCH * HEADS), dim3(256), 0, stream>>>(
            Q, ks, vs, nullptr, nullptr, ctx);
    }

    // 3) out = ctx @ Wo
    if (mid_ws) {
        proj_mfma_kernel<0><<<dim3(M / 64, EMB / 64), dim3(256), 0, stream>>>(ctx, wo, out);
    } else {
        proj_fp32_kernel<<<dim3(M / 8), dim3(256), 0, stream>>>(ctx, wo, out);
    }
}

// Round 8
// 282.255 us; speedup vs baseline: 1.1433x; 1.1433x over previous
//
#include <hip/hip_runtime.h>
#include <hip/hip_bf16.h>

#define EMB 512
#define HEADS 8
#define KD 64
#define SEQ 2048
#define BATCH 4

typedef __attribute__((ext_vector_type(8))) short bf16x8;
typedef __attribute__((ext_vector_type(4))) float f32x4;

__device__ __forceinline__ unsigned short f2bf(float x) {
    union { float f; unsigned u; } v; v.f = x;
    unsigned r = v.u + 0x7fff + ((v.u >> 16) & 1);   // RNE
    return (unsigned short)(r >> 16);
}
__device__ __forceinline__ float bf2f(unsigned short b) {
    union { unsigned u; float f; } v; v.u = ((unsigned)b) << 16;
    return v.f;
}

// ---------------------------------------------------------------------------
// Prep: K fp32 -> per-(bh,tile) images [hi 64x64][lo 64x64] bf16 (contiguous)
// ---------------------------------------------------------------------------
__global__ __launch_bounds__(256) void prep_k_kernel(const float* __restrict__ K,
                                                     unsigned short* __restrict__ kimg) {
    const int bt = blockIdx.x;                       // bh*32 + tile
    const float4* src = (const float4*)(K + (size_t)bt * 4096);
    unsigned short* dhi = kimg + (size_t)bt * 8192;
    unsigned short* dlo = dhi + 4096;
#pragma unroll
    for (int it = 0; it < 4; ++it) {
        const int idx = threadIdx.x + it * 256;
        const float4 v = src[idx];
        const unsigned short h0 = f2bf(v.x), h1 = f2bf(v.y),
                             h2 = f2bf(v.z), h3 = f2bf(v.w);
        *(uint2*)&dhi[idx * 4] = make_uint2(
            (unsigned)h0 | ((unsigned)h1 << 16),
            (unsigned)h2 | ((unsigned)h3 << 16));
        *(uint2*)&dlo[idx * 4] = make_uint2(
            (unsigned)f2bf(v.x - bf2f(h0)) | ((unsigned)f2bf(v.y - bf2f(h1)) << 16),
            (unsigned)f2bf(v.z - bf2f(h2)) | ((unsigned)f2bf(v.w - bf2f(h3)) << 16));
    }
}

// ---------------------------------------------------------------------------
// Prep: V fp32 -> per-(bh,tile) transposed images [d 64][s 64] bf16
// ---------------------------------------------------------------------------
__global__ __launch_bounds__(256) void prep_v_kernel(const float* __restrict__ V,
                                                     unsigned short* __restrict__ vimg) {
    const int bt = blockIdx.x;
    const float* src = V + (size_t)bt * 4096;
    unsigned short* dst = vimg + (size_t)bt * 4096;
#pragma unroll
    for (int it = 0; it < 2; ++it) {
        const int idx = threadIdx.x + it * 256;
        const int sp  = idx & 31;
        const int d4  = (idx >> 5) << 2;
        const float4 a = *(const float4*)(src + (2 * sp) * KD + d4);
        const float4 b = *(const float4*)(src + (2 * sp + 1) * KD + d4);
#pragma unroll
        for (int j = 0; j < 4; ++j) {
            const float aj = (&a.x)[j], bj = (&b.x)[j];
            *(unsigned*)&dst[(d4 + j) * 64 + 2 * sp] =
                (unsigned)f2bf(aj) | ((unsigned)f2bf(bj) << 16);
        }
    }
}

// ---------------------------------------------------------------------------
// MFMA flash attention, QB=64 (grid 1024 -> 4 blocks/CU), split-bf16 QK^T.
// PREP=1: K/V staged by pure uint4 copy from pre-converted images.
// PREP=0: in-kernel fp32->bf16 conversion staging (ws-too-small fallback).
// ---------------------------------------------------------------------------
template <int PREP>
__global__ __launch_bounds__(256) void attn3_kernel(const float* __restrict__ Q,
                                                    const float* __restrict__ Keys,
                                                    const float* __restrict__ Vals,
                                                    const unsigned short* __restrict__ kimg,
                                                    const unsigned short* __restrict__ vimg,
                                                    float* __restrict__ out) {
    constexpr int NT  = 64;
    constexpr int LDK = 72;

    __shared__ unsigned short k_s[2][NT][LDK];
    __shared__ unsigned short v_t[KD][LDK];
    __shared__ unsigned short p_s[4][16][LDK];

    const int t  = threadIdx.x;
    const int w  = t >> 6;
    const int l  = t & 63;
    const int g  = l >> 4;
    const int ln = l & 15;

    const int bh = blockIdx.y;
    const int q0 = blockIdx.x * 64 + w * 16;

    const float* kbase = Keys + (size_t)bh * SEQ * KD;
    const float* vbase = Vals + (size_t)bh * SEQ * KD;
    const float* qptr  = Q + ((size_t)bh * SEQ + q0 + ln) * KD;

    // Q fragments hi+lo (B-operand: col q=ln, k=d=g*8+j+32kk), pre-scaled 1/8
    bf16x8 qhi[2], qlo[2];
#pragma unroll
    for (int kk = 0; kk < 2; ++kk) {
        const float* p = qptr + g * 8 + 32 * kk;
#pragma unroll
        for (int j = 0; j < 8; ++j) {
            const float x = p[j] * 0.125f;
            const unsigned short h = f2bf(x);
            qhi[kk][j] = (short)h;
            qlo[kk][j] = (short)f2bf(x - bf2f(h));
        }
    }

    f32x4 acc[4];
#pragma unroll
    for (int db = 0; db < 4; ++db) acc[db] = (f32x4){0.f, 0.f, 0.f, 0.f};
    float m_run = -1e30f, l_run = 0.0f;

    for (int tile = 0; tile < SEQ / NT; ++tile) {
        __syncthreads();

        if (PREP) {
            // ---- pure-copy staging from pre-converted images ----
            const uint4* ksrc = (const uint4*)(kimg + (size_t)(bh * 32 + tile) * 8192);
#pragma unroll
            for (int it = 0; it < 4; ++it) {
                const int idx = t + it * 256;            // 0..1023 uint4s
                const int hl  = idx >> 9;
                const int rem = idx & 511;
                *(uint4*)&k_s[hl][rem >> 3][(rem & 7) * 8] = ksrc[idx];
            }
            const uint4* vsrc = (const uint4*)(vimg + (size_t)(bh * 32 + tile) * 4096);
#pragma unroll
            for (int it = 0; it < 2; ++it) {
                const int idx = t + it * 256;            // 0..511 uint4s
                *(uint4*)&v_t[idx >> 3][(idx & 7) * 8] = vsrc[idx];
            }
        } else {
            const float* kt = kbase + (size_t)tile * NT * KD;
            const float* vt = vbase + (size_t)tile * NT * KD;
#pragma unroll
            for (int it = 0; it < 4; ++it) {
                const int idx = t + it * 256;
                const int s   = idx >> 4;
                const int d4  = (idx & 15) << 2;
                const float4 kv = *(const float4*)(kt + s * KD + d4);
                unsigned short h0 = f2bf(kv.x), h1 = f2bf(kv.y),
                               h2 = f2bf(kv.z), h3 = f2bf(kv.w);
                *(uint2*)&k_s[0][s][d4] = make_uint2(
                    (unsigned)h0 | ((unsigned)h1 << 16),
                    (unsigned)h2 | ((unsigned)h3 << 16));
                *(uint2*)&k_s[1][s][d4] = make_uint2(
                    (unsigned)f2bf(kv.x - bf2f(h0)) | ((unsigned)f2bf(kv.y - bf2f(h1)) << 16),
                    (unsigned)f2bf(kv.z - bf2f(h2)) | ((unsigned)f2bf(kv.w - bf2f(h3)) << 16));
            }
#pragma unroll
            for (int it = 0; it < 2; ++it) {
                const int idx = t + it * 256;
                const int sp  = idx & 31;
                const int d4  = (idx >> 5) << 2;
                const float* v0 = vt + (2 * sp) * KD + d4;
                const float4 a = *(const float4*)v0;
                const float4 b = *(const float4*)(v0 + KD);
#pragma unroll
                for (int j = 0; j < 4; ++j) {
                    const float aj = (&a.x)[j], bj = (&b.x)[j];
                    *(unsigned*)&v_t[d4 + j][2 * sp] =
                        (unsigned)f2bf(aj) | ((unsigned)f2bf(bj) << 16);
                }
            }
        }
        __syncthreads();

        // ---- S^T = K·Q^T, 3-term split-bf16 ----
        f32x4 st[4];
#pragma unroll
        for (int sb = 0; sb < 4; ++sb) {
            f32x4 c = (f32x4){0.f, 0.f, 0.f, 0.f};
#pragma unroll
            for (int kk = 0; kk < 2; ++kk) {
                const bf16x8 khi = *(const bf16x8*)&k_s[0][sb * 16 + ln][g * 8 + 32 * kk];
                const bf16x8 klo = *(const bf16x8*)&k_s[1][sb * 16 + ln][g * 8 + 32 * kk];
                c = __builtin_amdgcn_mfma_f32_16x16x32_bf16(klo, qhi[kk], c, 0, 0, 0);
                c = __builtin_amdgcn_mfma_f32_16x16x32_bf16(khi, qlo[kk], c, 0, 0, 0);
                c = __builtin_amdgcn_mfma_f32_16x16x32_bf16(khi, qhi[kk], c, 0, 0, 0);
            }
            st[sb] = c;   // S^T[16sb+4g+r][q=ln]
        }

        // ---- online softmax over s for q=ln ----
        float tm = st[0][0];
#pragma unroll
        for (int sb = 0; sb < 4; ++sb)
#pragma unroll
            for (int r = 0; r < 4; ++r) tm = fmaxf(tm, st[sb][r]);
        tm = fmaxf(tm, __shfl_xor(tm, 16));
        tm = fmaxf(tm, __shfl_xor(tm, 32));

        const float m_new  = fmaxf(m_run, tm);
        const float scalef = __expf(m_run - m_new);
        m_run = m_new;

        float rs = 0.f;
#pragma unroll
        for (int sb = 0; sb < 4; ++sb) {
            const float p0 = __expf(st[sb][0] - m_new);
            const float p1 = __expf(st[sb][1] - m_new);
            const float p2 = __expf(st[sb][2] - m_new);
            const float p3 = __expf(st[sb][3] - m_new);
            rs += (p0 + p1) + (p2 + p3);
            const unsigned lo = (unsigned)f2bf(p0) | ((unsigned)f2bf(p1) << 16);
            const unsigned hi = (unsigned)f2bf(p2) | ((unsigned)f2bf(p3) << 16);
            *(uint2*)&p_s[w][ln][sb * 16 + g * 4] = make_uint2(lo, hi);
        }
        rs += __shfl_xor(rs, 16);
        rs += __shfl_xor(rs, 32);
        l_run = l_run * scalef + rs;

#pragma unroll
        for (int r = 0; r < 4; ++r) {
            const float sr = __shfl(scalef, 4 * g + r);
#pragma unroll
            for (int db = 0; db < 4; ++db) acc[db][r] *= sr;
        }

        // ---- PV (p_s per-wave: same-wave write->read needs no barrier) ----
        bf16x8 pa[2];
#pragma unroll
        for (int kk = 0; kk < 2; ++kk)
            pa[kk] = *(const bf16x8*)&p_s[w][ln][g * 8 + 32 * kk];
#pragma unroll
        for (int db = 0; db < 4; ++db) {
            f32x4 c = acc[db];
#pragma unroll
            for (int kk = 0; kk < 2; ++kk) {
                const bf16x8 vb = *(const bf16x8*)&v_t[ln + 16 * db][g * 8 + 32 * kk];
                c = __builtin_amdgcn_mfma_f32_16x16x32_bf16(pa[kk], vb, c, 0, 0, 0);
            }
            acc[db] = c;
        }
    }

    // ---- epilogue ----
    const float invl = 1.0f / l_run;
    const int b = bh >> 3, h = bh & 7;
#pragma unroll
    for (int r = 0; r < 4; ++r) {
        const float iv = __shfl(invl, 4 * g + r);
        float* orow = out + ((size_t)(b * SEQ + q0 + 4 * g + r) * EMB) + h * KD + ln;
#pragma unroll
        for (int db = 0; db < 4; ++db) orow[16 * db] = acc[db][r] * iv;
    }
}

// ---------------------------------------------------------------------------
// MFMA projection GEMM, split-bf16 (3-term). Tile 64x64, BK=64, 4 waves.
// TRANSQ=1: scatter output to [B,H,S,64]. NOT in-place safe.
// ---------------------------------------------------------------------------
template <int TRANSQ>
__global__ __launch_bounds__(256) void proj_mfma_kernel(const float* __restrict__ in,
                                                        const float* __restrict__ W,
                                                        float* __restrict__ out) {
    __shared__ unsigned short x_s[2][64][72];
    __shared__ unsigned short w_t[2][64][72];

    const int t  = threadIdx.x;
    const int w  = t >> 6;
    const int l  = t & 63;
    const int g  = l >> 4;
    const int ln = l & 15;

    const int row0 = blockIdx.x * 64;
    const int n0   = blockIdx.y * 64;

    f32x4 acc[4];
#pragma unroll
    for (int cb = 0; cb < 4; ++cb) acc[cb] = (f32x4){0.f, 0.f, 0.f, 0.f};

    for (int ch = 0; ch < EMB / 64; ++ch) {
        __syncthreads();
#pragma unroll
        for (int it = 0; it < 4; ++it) {
            const int idx = t + it * 256;
            const int s   = idx >> 4;
            const int d4  = (idx & 15) << 2;
            const float4 xv = *(const float4*)(in + (size_t)(row0 + s) * EMB + ch * 64 + d4);
            const unsigned short h0 = f2bf(xv.x), h1 = f2bf(xv.y),
                                 h2 = f2bf(xv.z), h3 = f2bf(xv.w);
            *(uint2*)&x_s[0][s][d4] = make_uint2(
                (unsigned)h0 | ((unsigned)h1 << 16),
                (unsigned)h2 | ((unsigned)h3 << 16));
            *(uint2*)&x_s[1][s][d4] = make_uint2(
                (unsigned)f2bf(xv.x - bf2f(h0)) | ((unsigned)f2bf(xv.y - bf2f(h1)) << 16),
                (unsigned)f2bf(xv.z - bf2f(h2)) | ((unsigned)f2bf(xv.w - bf2f(h3)) << 16));
        }
#pragma unroll
        for (int it = 0; it < 2; ++it) {
            const int idx = t + it * 256;
            const int sp  = idx & 31;
            const int c4  = (idx >> 5) << 2;
            const float* wrow = W + (size_t)(ch * 64 + 2 * sp) * EMB + n0 + c4;
            const float4 a = *(const float4*)wrow;
            const float4 b = *(const float4*)(wrow + EMB);
#pragma unroll
            for (int j = 0; j < 4; ++j) {
                const float aj = (&a.x)[j], bj = (&b.x)[j];
                const unsigned short ah = f2bf(aj), bh = f2bf(bj);
                *(unsigned*)&w_t[0][c4 + j][2 * sp] =
                    (unsigned)ah | ((unsigned)bh << 16);
                *(unsigned*)&w_t[1][c4 + j][2 * sp] =
                    (unsigned)f2bf(aj - bf2f(ah)) | ((unsigned)f2bf(bj - bf2f(bh)) << 16);
            }
        }
        __syncthreads();

        bf16x8 ah[2], al[2];
#pragma unroll
        for (int kk = 0; kk < 2; ++kk) {
            ah[kk] = *(const bf16x8*)&x_s[0][w * 16 + ln][g * 8 + 32 * kk];
            al[kk] = *(const bf16x8*)&x_s[1][w * 16 + ln][g * 8 + 32 * kk];
        }
#pragma unroll
        for (int cb = 0; cb < 4; ++cb) {
            f32x4 c = acc[cb];
#pragma unroll
            for (int kk = 0; kk < 2; ++kk) {
                const bf16x8 bh = *(const bf16x8*)&w_t[0][cb * 16 + ln][g * 8 + 32 * kk];
                const bf16x8 bl = *(const bf16x8*)&w_t[1][cb * 16 + ln][g * 8 + 32 * kk];
                c = __builtin_amdgcn_mfma_f32_16x16x32_bf16(al[kk], bh, c, 0, 0, 0);
                c = __builtin_amdgcn_mfma_f32_16x16x32_bf16(ah[kk], bl, c, 0, 0, 0);
                c = __builtin_amdgcn_mfma_f32_16x16x32_bf16(ah[kk], bh, c, 0, 0, 0);
            }
            acc[cb] = c;
        }
    }

#pragma unroll
    for (int cb = 0; cb < 4; ++cb) {
#pragma unroll
        for (int r = 0; r < 4; ++r) {
            const int row = row0 + w * 16 + 4 * g + r;
            const int col = n0 + cb * 16 + ln;
            if (TRANSQ) {
                const int b = row >> 11, s = row & 2047;
                const int h = col >> 6, k = col & 63;
                out[((size_t)(b * HEADS + h) * SEQ + s) * KD + k] = acc[cb][r];
            } else {
                out[(size_t)row * EMB + col] = acc[cb][r];
            }
        }
    }
}

// ---------------------------------------------------------------------------
// fp32 out-projection fallback (in-place safe: 8 rows fully staged first)
// ---------------------------------------------------------------------------
__global__ __launch_bounds__(256) void proj_fp32_kernel(const float* __restrict__ in,
                                                        const float* __restrict__ W,
                                                        float* __restrict__ out) {
    __shared__ float x_s[8][EMB];
    const int block_row = blockIdx.x * 8;

    const float4* in4 = (const float4*)(in + (size_t)block_row * EMB);
    float4* xs4 = (float4*)(&x_s[0][0]);
    for (int i = threadIdx.x; i < 8 * EMB / 4; i += 256) xs4[i] = in4[i];
    __syncthreads();

    const int n  = (threadIdx.x & 127) * 4;
    const int rg = threadIdx.x >> 7;

    float acc[4][4] = {};
    for (int e = 0; e < EMB; ++e) {
        const float4 w4 = *(const float4*)(W + (size_t)e * EMB + n);
#pragma unroll
        for (int rr = 0; rr < 4; ++rr) {
            const float xv = x_s[rg + rr * 2][e];
            acc[rr][0] += xv * w4.x;
            acc[rr][1] += xv * w4.y;
            acc[rr][2] += xv * w4.z;
            acc[rr][3] += xv * w4.w;
        }
    }
#pragma unroll
    for (int rr = 0; rr < 4; ++rr) {
        const int row = block_row + rg + rr * 2;
        float4 o;
        o.x = acc[rr][0]; o.y = acc[rr][1]; o.z = acc[rr][2]; o.w = acc[rr][3];
        *(float4*)(out + (size_t)row * EMB + n) = o;
    }
}

// ---------------------------------------------------------------------------
extern "C" void kernel_launch(void* const* d_in, const int* in_sizes, int n_in,
                              void* d_out, int out_size, void* d_ws, size_t ws_size,
                              hipStream_t stream) {
    const float* x  = (const float*)d_in[0];
    const float* ks = (const float*)d_in[1];
    const float* vs = (const float*)d_in[2];
    const float* wq = (const float*)d_in[3];
    const float* wo = (const float*)d_in[4];
    float* out = (float*)d_out;

    const size_t QBYTES  = (size_t)BATCH * HEADS * SEQ * KD * 4;      // 16.8 MB
    const size_t CBYTES  = (size_t)BATCH * SEQ * EMB * 4;             // 16.8 MB
    const size_t KIBYTES = (size_t)BATCH * HEADS * SEQ * KD * 2 * 2;  // 16.8 MB
    const size_t VIBYTES = (size_t)BATCH * HEADS * SEQ * KD * 2;      // 8.4 MB

    float* Q = (float*)d_ws;
    const bool mid_ws  = ws_size >= QBYTES + CBYTES;
    const bool full_ws = ws_size >= QBYTES + CBYTES + KIBYTES + VIBYTES;
    float* ctx = mid_ws ? (float*)((char*)d_ws + QBYTES) : out;
    unsigned short* kimg = (unsigned short*)((char*)d_ws + QBYTES + CBYTES);
    unsigned short* vimg = (unsigned short*)((char*)d_ws + QBYTES + CBYTES + KIBYTES);

    const int M = BATCH * SEQ;  // 8192

    // 1) Q = x @ Wq (MFMA split-bf16), scattered to [B,H,S,64]
    proj_mfma_kernel<1><<<dim3(M / 64, EMB / 64), dim3(256), 0, stream>>>(x, wq, Q);

    // 2) flash attention (QB=64: grid 1024 -> 4 blocks/CU)
    if (full_ws) {
        prep_k_kernel<<<dim3(BATCH * HEADS * 32), dim3(256), 0, stream>>>(ks, kimg);
        prep_v_kernel<<<dim3(BATCH * HEADS * 32), dim3(256), 0, stream>>>(vs, vimg);
        attn3_kernel<1><<<dim3(SEQ / 64, BATCH * HEADS), dim3(256), 0, stream>>>(
            Q, ks, vs, kimg, vimg, ctx);
    } else {
        attn3_kernel<0><<<dim3(SEQ / 64, BATCH * HEADS), dim3(256), 0, stream>>>(
            Q, ks, vs, nullptr, nullptr, ctx);
    }

    // 3) out = ctx @ Wo
    if (mid_ws) {
        proj_mfma_kernel<0><<<dim3(M / 64, EMB / 64), dim3(256), 0, stream>>>(ctx, wo, out);
    } else {
        proj_fp32_kernel<<<dim3(M / 8), dim3(256), 0, stream>>>(ctx, wo, out);
    }
}

// Round 9
// 245.303 us; speedup vs baseline: 1.3155x; 1.1506x over previous
//
#include <hip/hip_runtime.h>
#include <hip/hip_bf16.h>

#define EMB 512
#define HEADS 8
#define KD 64
#define SEQ 2048
#define BATCH 4

typedef __attribute__((ext_vector_type(8))) short bf16x8;
typedef __attribute__((ext_vector_type(4))) float f32x4;

__device__ __forceinline__ unsigned short f2bf(float x) {
    union { float f; unsigned u; } v; v.f = x;
    unsigned r = v.u + 0x7fff + ((v.u >> 16) & 1);   // RNE
    return (unsigned short)(r >> 16);
}
__device__ __forceinline__ float bf2f(unsigned short b) {
    union { unsigned u; float f; } v; v.u = ((unsigned)b) << 16;
    return v.f;
}
__device__ __forceinline__ unsigned pk2(float a, float b) {  // packed bf16 pair (RNE)
    __hip_bfloat162 h = __float22bfloat162_rn(float2{a, b});
    unsigned u; __builtin_memcpy(&u, &h, 4); return u;
}

// ===========================================================================
//                                TIER A
// ===========================================================================
// Fused prep: x -> hi/lo tile images; Wq -> W^T hi/lo; Wo -> W^T bf16;
// K -> hi/lo images; V -> V^T images. Grid 3200 blocks.
// Tile layouts (64x64, per-tile contiguous):
//   ximg  tile tb=rb*8+ch: [hi 64r x 64k][lo ...]          (8192 shorts)
//   wqimg tile nb*8+ch:    [hi 64col x 64k][lo ...]        (8192 shorts)
//   woimg tile nb*8+ch:    [64col x 64k]                   (4096 shorts)
//   kimg  tile bh*32+tl:   [hi 64s x 64d][lo ...]          (8192 shorts)
//   vimg  tile bh*32+tl:   [64d x 64s]                     (4096 shorts)
// ---------------------------------------------------------------------------
__global__ __launch_bounds__(256) void prep_all_kernel(
    const float* __restrict__ x,  const float* __restrict__ wq,
    const float* __restrict__ wo, const float* __restrict__ K,
    const float* __restrict__ V,
    unsigned short* __restrict__ ximg, unsigned short* __restrict__ wqimg,
    unsigned short* __restrict__ woimg, unsigned short* __restrict__ kimg,
    unsigned short* __restrict__ vimg) {
    const int bid = blockIdx.x;
    const int t   = threadIdx.x;

    if (bid < 1024) {
        // ---- x tile (row-major within tile, hi/lo) ----
        const int rb = bid >> 3, ch = bid & 7;
        const float* src = x + (size_t)rb * 64 * EMB + ch * 64;
        unsigned short* dhi = ximg + (size_t)bid * 8192;
        unsigned short* dlo = dhi + 4096;
#pragma unroll
        for (int it = 0; it < 4; ++it) {
            const int idx = t + it * 256;            // 0..1023
            const int row = idx >> 4, c4 = (idx & 15) << 2;
            const float4 v = *(const float4*)(src + (size_t)row * EMB + c4);
            const unsigned short h0 = f2bf(v.x), h1 = f2bf(v.y),
                                 h2 = f2bf(v.z), h3 = f2bf(v.w);
            *(uint2*)&dhi[row * 64 + c4] = make_uint2(
                (unsigned)h0 | ((unsigned)h1 << 16),
                (unsigned)h2 | ((unsigned)h3 << 16));
            *(uint2*)&dlo[row * 64 + c4] = make_uint2(
                (unsigned)f2bf(v.x - bf2f(h0)) | ((unsigned)f2bf(v.y - bf2f(h1)) << 16),
                (unsigned)f2bf(v.z - bf2f(h2)) | ((unsigned)f2bf(v.w - bf2f(h3)) << 16));
        }
    } else if (bid < 1152) {
        // ---- W tiles, transposed [col][k]; wq hi/lo, wo hi only ----
        int widx = bid - 1024;
        const bool isq = widx < 64;
        if (!isq) widx -= 64;
        const int nb = widx >> 3, ch = widx & 7;
        const float* src = (isq ? wq : wo) + (size_t)(ch * 64) * EMB + nb * 64;
        unsigned short* dhi = isq ? (wqimg + (size_t)widx * 8192)
                                  : (woimg + (size_t)widx * 4096);
        unsigned short* dlo = dhi + 4096;
#pragma unroll
        for (int it = 0; it < 2; ++it) {
            const int idx = t + it * 256;            // 0..511
            const int sp  = idx & 31;                // k-pair
            const int c4  = (idx >> 5) << 2;         // col
            const float* r0 = src + (size_t)(2 * sp) * EMB + c4;
            const float4 a = *(const float4*)r0;
            const float4 b = *(const float4*)(r0 + EMB);
#pragma unroll
            for (int j = 0; j < 4; ++j) {
                const float aj = (&a.x)[j], bj = (&b.x)[j];
                const unsigned short ah = f2bf(aj), bh = f2bf(bj);
                *(unsigned*)&dhi[(c4 + j) * 64 + 2 * sp] =
                    (unsigned)ah | ((unsigned)bh << 16);
                if (isq)
                    *(unsigned*)&dlo[(c4 + j) * 64 + 2 * sp] =
                        (unsigned)f2bf(aj - bf2f(ah)) | ((unsigned)f2bf(bj - bf2f(bh)) << 16);
            }
        }
    } else if (bid < 2176) {
        // ---- K tile (row-major, hi/lo) ----
        const int kt = bid - 1152;
        const float4* src = (const float4*)(K + (size_t)kt * 4096);
        unsigned short* dhi = kimg + (size_t)kt * 8192;
        unsigned short* dlo = dhi + 4096;
#pragma unroll
        for (int it = 0; it < 4; ++it) {
            const int idx = t + it * 256;
            const float4 v = src[idx];
            const unsigned short h0 = f2bf(v.x), h1 = f2bf(v.y),
                                 h2 = f2bf(v.z), h3 = f2bf(v.w);
            *(uint2*)&dhi[idx * 4] = make_uint2(
                (unsigned)h0 | ((unsigned)h1 << 16),
                (unsigned)h2 | ((unsigned)h3 << 16));
            *(uint2*)&dlo[idx * 4] = make_uint2(
                (unsigned)f2bf(v.x - bf2f(h0)) | ((unsigned)f2bf(v.y - bf2f(h1)) << 16),
                (unsigned)f2bf(v.z - bf2f(h2)) | ((unsigned)f2bf(v.w - bf2f(h3)) << 16));
        }
    } else {
        // ---- V tile transposed [d][s] ----
        const int vt = bid - 2176;
        const float* src = V + (size_t)vt * 4096;
        unsigned short* dst = vimg + (size_t)vt * 4096;
#pragma unroll
        for (int it = 0; it < 2; ++it) {
            const int idx = t + it * 256;
            const int sp  = idx & 31;
            const int d4  = (idx >> 5) << 2;
            const float4 a = *(const float4*)(src + (2 * sp) * KD + d4);
            const float4 b = *(const float4*)(src + (2 * sp + 1) * KD + d4);
#pragma unroll
            for (int j = 0; j < 4; ++j) {
                *(unsigned*)&dst[(d4 + j) * 64 + 2 * sp] =
                    (unsigned)f2bf((&a.x)[j]) | ((unsigned)f2bf((&b.x)[j]) << 16);
            }
        }
    }
}

// ---------------------------------------------------------------------------
// Q projection from images: pure-copy staging, 3-term split-bf16 MFMA.
// Writes Q (x0.125) as bf16 hi/lo images [B,H,S,64].
// ---------------------------------------------------------------------------
__global__ __launch_bounds__(256) void proj_q_kernel(
    const unsigned short* __restrict__ ximg,
    const unsigned short* __restrict__ wqimg,
    unsigned short* __restrict__ qhi_img,
    unsigned short* __restrict__ qlo_img) {
    __shared__ unsigned short x_s[2][64][72];
    __shared__ unsigned short w_t[2][64][72];

    const int t  = threadIdx.x;
    const int w  = t >> 6;
    const int l  = t & 63;
    const int g  = l >> 4;
    const int ln = l & 15;

    const int rb = blockIdx.x;    // row block
    const int nb = blockIdx.y;    // col block (= head)

    f32x4 acc[4];
#pragma unroll
    for (int cb = 0; cb < 4; ++cb) acc[cb] = (f32x4){0.f, 0.f, 0.f, 0.f};

    for (int ch = 0; ch < 8; ++ch) {
        __syncthreads();
        const uint4* xs = (const uint4*)(ximg + (size_t)(rb * 8 + ch) * 8192);
        const uint4* ws = (const uint4*)(wqimg + (size_t)(nb * 8 + ch) * 8192);
#pragma unroll
        for (int it = 0; it < 4; ++it) {
            const int idx = t + it * 256;            // 0..1023
            const int hl  = idx >> 9;
            const int rem = idx & 511;
            *(uint4*)&x_s[hl][rem >> 3][(rem & 7) * 8] = xs[idx];
            *(uint4*)&w_t[hl][rem >> 3][(rem & 7) * 8] = ws[idx];
        }
        __syncthreads();

        bf16x8 ah[2], al[2];
#pragma unroll
        for (int kk = 0; kk < 2; ++kk) {
            ah[kk] = *(const bf16x8*)&x_s[0][w * 16 + ln][g * 8 + 32 * kk];
            al[kk] = *(const bf16x8*)&x_s[1][w * 16 + ln][g * 8 + 32 * kk];
        }
#pragma unroll
        for (int cb = 0; cb < 4; ++cb) {
            f32x4 c = acc[cb];
#pragma unroll
            for (int kk = 0; kk < 2; ++kk) {
                const bf16x8 bh = *(const bf16x8*)&w_t[0][cb * 16 + ln][g * 8 + 32 * kk];
                const bf16x8 bl = *(const bf16x8*)&w_t[1][cb * 16 + ln][g * 8 + 32 * kk];
                c = __builtin_amdgcn_mfma_f32_16x16x32_bf16(al[kk], bh, c, 0, 0, 0);
                c = __builtin_amdgcn_mfma_f32_16x16x32_bf16(ah[kk], bl, c, 0, 0, 0);
                c = __builtin_amdgcn_mfma_f32_16x16x32_bf16(ah[kk], bh, c, 0, 0, 0);
            }
            acc[cb] = c;
        }
    }

    // epilogue: scale by 1/8, split hi/lo, scatter to [B,H,S,64]
#pragma unroll
    for (int cb = 0; cb < 4; ++cb) {
#pragma unroll
        for (int r = 0; r < 4; ++r) {
            const int row = rb * 64 + w * 16 + 4 * g + r;   // global M row
            const int k   = cb * 16 + ln;                   // within-head dim
            const float v = acc[cb][r] * 0.125f;
            const unsigned short hi = f2bf(v);
            const unsigned short lo = f2bf(v - bf2f(hi));
            const size_t off = ((size_t)((row >> 11) * HEADS + nb) * SEQ + (row & 2047)) * KD + k;
            qhi_img[off] = hi;
            qlo_img[off] = lo;
        }
    }
}

// ---------------------------------------------------------------------------
// Out projection from ctx image (bf16) + Wo image (bf16): 1-term MFMA.
// ---------------------------------------------------------------------------
__global__ __launch_bounds__(256) void proj_o_kernel(
    const unsigned short* __restrict__ ctximg,
    const unsigned short* __restrict__ woimg,
    float* __restrict__ out) {
    __shared__ unsigned short x_s[64][72];
    __shared__ unsigned short w_t[64][72];

    const int t  = threadIdx.x;
    const int w  = t >> 6;
    const int l  = t & 63;
    const int g  = l >> 4;
    const int ln = l & 15;

    const int rb = blockIdx.x;
    const int nb = blockIdx.y;

    f32x4 acc[4];
#pragma unroll
    for (int cb = 0; cb < 4; ++cb) acc[cb] = (f32x4){0.f, 0.f, 0.f, 0.f};

    for (int ch = 0; ch < 8; ++ch) {
        __syncthreads();
        const uint4* xs = (const uint4*)(ctximg + (size_t)(rb * 8 + ch) * 4096);
        const uint4* ws = (const uint4*)(woimg + (size_t)(nb * 8 + ch) * 4096);
#pragma unroll
        for (int it = 0; it < 2; ++it) {
            const int idx = t + it * 256;            // 0..511
            *(uint4*)&x_s[idx >> 3][(idx & 7) * 8] = xs[idx];
            *(uint4*)&w_t[idx >> 3][(idx & 7) * 8] = ws[idx];
        }
        __syncthreads();

        bf16x8 ah[2];
#pragma unroll
        for (int kk = 0; kk < 2; ++kk)
            ah[kk] = *(const bf16x8*)&x_s[w * 16 + ln][g * 8 + 32 * kk];
#pragma unroll
        for (int cb = 0; cb < 4; ++cb) {
            f32x4 c = acc[cb];
#pragma unroll
            for (int kk = 0; kk < 2; ++kk) {
                const bf16x8 bh = *(const bf16x8*)&w_t[cb * 16 + ln][g * 8 + 32 * kk];
                c = __builtin_amdgcn_mfma_f32_16x16x32_bf16(ah[kk], bh, c, 0, 0, 0);
            }
            acc[cb] = c;
        }
    }

#pragma unroll
    for (int cb = 0; cb < 4; ++cb) {
#pragma unroll
        for (int r = 0; r < 4; ++r) {
            const int row = rb * 64 + w * 16 + 4 * g + r;
            const int col = nb * 64 + cb * 16 + ln;
            out[(size_t)row * EMB + col] = acc[cb][r];
        }
    }
}

// ---------------------------------------------------------------------------
// MFMA flash attention from images. Q bf16 hi/lo direct fragment loads,
// pure-copy K/V staging, cvt_pk P-pack, ctx written as bf16 tile image.
// ---------------------------------------------------------------------------
__global__ __launch_bounds__(256) void attn4_kernel(
    const unsigned short* __restrict__ qhi_img,
    const unsigned short* __restrict__ qlo_img,
    const unsigned short* __restrict__ kimg,
    const unsigned short* __restrict__ vimg,
    unsigned short* __restrict__ ctximg) {
    constexpr int NT  = 64;
    constexpr int LDK = 72;

    __shared__ unsigned short k_s[2][NT][LDK];
    __shared__ unsigned short v_t[KD][LDK];
    __shared__ unsigned short p_s[4][16][LDK];

    const int t  = threadIdx.x;
    const int w  = t >> 6;
    const int l  = t & 63;
    const int g  = l >> 4;
    const int ln = l & 15;

    const int bh = blockIdx.y;
    const int q0 = blockIdx.x * 64 + w * 16;

    // Q fragments: direct bf16 loads (conversion + 0.125 folded into proj_q)
    bf16x8 qhi[2], qlo[2];
    {
        const size_t qoff = ((size_t)bh * SEQ + q0 + ln) * KD;
#pragma unroll
        for (int kk = 0; kk < 2; ++kk) {
            qhi[kk] = *(const bf16x8*)&qhi_img[qoff + g * 8 + 32 * kk];
            qlo[kk] = *(const bf16x8*)&qlo_img[qoff + g * 8 + 32 * kk];
        }
    }

    f32x4 acc[4];
#pragma unroll
    for (int db = 0; db < 4; ++db) acc[db] = (f32x4){0.f, 0.f, 0.f, 0.f};
    float m_run = -1e30f, l_run = 0.0f;

    for (int tile = 0; tile < SEQ / NT; ++tile) {
        __syncthreads();

        const uint4* ksrc = (const uint4*)(kimg + (size_t)(bh * 32 + tile) * 8192);
#pragma unroll
        for (int it = 0; it < 4; ++it) {
            const int idx = t + it * 256;
            const int hl  = idx >> 9;
            const int rem = idx & 511;
            *(uint4*)&k_s[hl][rem >> 3][(rem & 7) * 8] = ksrc[idx];
        }
        const uint4* vsrc = (const uint4*)(vimg + (size_t)(bh * 32 + tile) * 4096);
#pragma unroll
        for (int it = 0; it < 2; ++it) {
            const int idx = t + it * 256;
            *(uint4*)&v_t[idx >> 3][(idx & 7) * 8] = vsrc[idx];
        }
        __syncthreads();

        // ---- S^T = K·Q^T, 3-term split-bf16 ----
        f32x4 st[4];
#pragma unroll
        for (int sb = 0; sb < 4; ++sb) {
            f32x4 c = (f32x4){0.f, 0.f, 0.f, 0.f};
#pragma unroll
            for (int kk = 0; kk < 2; ++kk) {
                const bf16x8 khi = *(const bf16x8*)&k_s[0][sb * 16 + ln][g * 8 + 32 * kk];
                const bf16x8 klo = *(const bf16x8*)&k_s[1][sb * 16 + ln][g * 8 + 32 * kk];
                c = __builtin_amdgcn_mfma_f32_16x16x32_bf16(klo, qhi[kk], c, 0, 0, 0);
                c = __builtin_amdgcn_mfma_f32_16x16x32_bf16(khi, qlo[kk], c, 0, 0, 0);
                c = __builtin_amdgcn_mfma_f32_16x16x32_bf16(khi, qhi[kk], c, 0, 0, 0);
            }
            st[sb] = c;   // S^T[16sb+4g+r][q=ln]
        }

        // ---- online softmax over s for q=ln ----
        float tm = st[0][0];
#pragma unroll
        for (int sb = 0; sb < 4; ++sb)
#pragma unroll
            for (int r = 0; r < 4; ++r) tm = fmaxf(tm, st[sb][r]);
        tm = fmaxf(tm, __shfl_xor(tm, 16));
        tm = fmaxf(tm, __shfl_xor(tm, 32));

        const float m_new  = fmaxf(m_run, tm);
        const float scalef = __expf(m_run - m_new);
        m_run = m_new;

        float rs = 0.f;
#pragma unroll
        for (int sb = 0; sb < 4; ++sb) {
            const float p0 = __expf(st[sb][0] - m_new);
            const float p1 = __expf(st[sb][1] - m_new);
            const float p2 = __expf(st[sb][2] - m_new);
            const float p3 = __expf(st[sb][3] - m_new);
            rs += (p0 + p1) + (p2 + p3);
            *(uint2*)&p_s[w][ln][sb * 16 + g * 4] =
                make_uint2(pk2(p0, p1), pk2(p2, p3));
        }
        rs += __shfl_xor(rs, 16);
        rs += __shfl_xor(rs, 32);
        l_run = l_run * scalef + rs;

#pragma unroll
        for (int r = 0; r < 4; ++r) {
            const float sr = __shfl(scalef, 4 * g + r);
#pragma unroll
            for (int db = 0; db < 4; ++db) acc[db][r] *= sr;
        }

        // ---- PV ----
        bf16x8 pa[2];
#pragma unroll
        for (int kk = 0; kk < 2; ++kk)
            pa[kk] = *(const bf16x8*)&p_s[w][ln][g * 8 + 32 * kk];
#pragma unroll
        for (int db = 0; db < 4; ++db) {
            f32x4 c = acc[db];
#pragma unroll
            for (int kk = 0; kk < 2; ++kk) {
                const bf16x8 vb = *(const bf16x8*)&v_t[ln + 16 * db][g * 8 + 32 * kk];
                c = __builtin_amdgcn_mfma_f32_16x16x32_bf16(pa[kk], vb, c, 0, 0, 0);
            }
            acc[db] = c;
        }
    }

    // ---- epilogue: normalize, write bf16 ctx tile image ----
    const float invl = 1.0f / l_run;
    const int rb  = (bh >> 3) * 32 + blockIdx.x;
    const int chh = bh & 7;
    unsigned short* cbase = ctximg + ((size_t)rb * 8 + chh) * 4096;
#pragma unroll
    for (int r = 0; r < 4; ++r) {
        const float iv = __shfl(invl, 4 * g + r);
        const int row = w * 16 + 4 * g + r;
#pragma unroll
        for (int db = 0; db < 4; ++db)
            cbase[row * 64 + db * 16 + ln] = f2bf(acc[db][r] * iv);
    }
}

// ===========================================================================
//                      TIER B (round-8 path, fallback)
// ===========================================================================
__global__ __launch_bounds__(256) void prep_k_kernel(const float* __restrict__ K,
                                                     unsigned short* __restrict__ kimg) {
    const int bt = blockIdx.x;
    const float4* src = (const float4*)(K + (size_t)bt * 4096);
    unsigned short* dhi = kimg + (size_t)bt * 8192;
    unsigned short* dlo = dhi + 4096;
#pragma unroll
    for (int it = 0; it < 4; ++it) {
        const int idx = threadIdx.x + it * 256;
        const float4 v = src[idx];
        const unsigned short h0 = f2bf(v.x), h1 = f2bf(v.y),
                             h2 = f2bf(v.z), h3 = f2bf(v.w);
        *(uint2*)&dhi[idx * 4] = make_uint2(
            (unsigned)h0 | ((unsigned)h1 << 16),
            (unsigned)h2 | ((unsigned)h3 << 16));
        *(uint2*)&dlo[idx * 4] = make_uint2(
            (unsigned)f2bf(v.x - bf2f(h0)) | ((unsigned)f2bf(v.y - bf2f(h1)) << 16),
            (unsigned)f2bf(v.z - bf2f(h2)) | ((unsigned)f2bf(v.w - bf2f(h3)) << 16));
    }
}

__global__ __launch_bounds__(256) void prep_v_kernel(const float* __restrict__ V,
                                                     unsigned short* __restrict__ vimg) {
    const int bt = blockIdx.x;
    const float* src = V + (size_t)bt * 4096;
    unsigned short* dst = vimg + (size_t)bt * 4096;
#pragma unroll
    for (int it = 0; it < 2; ++it) {
        const int idx = threadIdx.x + it * 256;
        const int sp  = idx & 31;
        const int d4  = (idx >> 5) << 2;
        const float4 a = *(const float4*)(src + (2 * sp) * KD + d4);
        const float4 b = *(const float4*)(src + (2 * sp + 1) * KD + d4);
#pragma unroll
        for (int j = 0; j < 4; ++j) {
            *(unsigned*)&dst[(d4 + j) * 64 + 2 * sp] =
                (unsigned)f2bf((&a.x)[j]) | ((unsigned)f2bf((&b.x)[j]) << 16);
        }
    }
}

template <int PREP>
__global__ __launch_bounds__(256) void attn3_kernel(const float* __restrict__ Q,
                                                    const float* __restrict__ Keys,
                                                    const float* __restrict__ Vals,
                                                    const unsigned short* __restrict__ kimg,
                                                    const unsigned short* __restrict__ vimg,
                                                    float* __restrict__ out) {
    constexpr int NT  = 64;
    constexpr int LDK = 72;

    __shared__ unsigned short k_s[2][NT][LDK];
    __shared__ unsigned short v_t[KD][LDK];
    __shared__ unsigned short p_s[4][16][LDK];

    const int t  = threadIdx.x;
    const int w  = t >> 6;
    const int l  = t & 63;
    const int g  = l >> 4;
    const int ln = l & 15;

    const int bh = blockIdx.y;
    const int q0 = blockIdx.x * 64 + w * 16;

    const float* kbase = Keys + (size_t)bh * SEQ * KD;
    const float* vbase = Vals + (size_t)bh * SEQ * KD;
    const float* qptr  = Q + ((size_t)bh * SEQ + q0 + ln) * KD;

    bf16x8 qhi[2], qlo[2];
#pragma unroll
    for (int kk = 0; kk < 2; ++kk) {
        const float* p = qptr + g * 8 + 32 * kk;
#pragma unroll
        for (int j = 0; j < 8; ++j) {
            const float xv = p[j] * 0.125f;
            const unsigned short h = f2bf(xv);
            qhi[kk][j] = (short)h;
            qlo[kk][j] = (short)f2bf(xv - bf2f(h));
        }
    }

    f32x4 acc[4];
#pragma unroll
    for (int db = 0; db < 4; ++db) acc[db] = (f32x4){0.f, 0.f, 0.f, 0.f};
    float m_run = -1e30f, l_run = 0.0f;

    for (int tile = 0; tile < SEQ / NT; ++tile) {
        __syncthreads();

        if (PREP) {
            const uint4* ksrc = (const uint4*)(kimg + (size_t)(bh * 32 + tile) * 8192);
#pragma unroll
            for (int it = 0; it < 4; ++it) {
                const int idx = t + it * 256;
                const int hl  = idx >> 9;
                const int rem = idx & 511;
                *(uint4*)&k_s[hl][rem >> 3][(rem & 7) * 8] = ksrc[idx];
            }
            const uint4* vsrc = (const uint4*)(vimg + (size_t)(bh * 32 + tile) * 4096);
#pragma unroll
            for (int it = 0; it < 2; ++it) {
                const int idx = t + it * 256;
                *(uint4*)&v_t[idx >> 3][(idx & 7) * 8] = vsrc[idx];
            }
        } else {
            const float* kt = kbase + (size_t)tile * NT * KD;
            const float* vt = vbase + (size_t)tile * NT * KD;
#pragma unroll
            for (int it = 0; it < 4; ++it) {
                const int idx = t + it * 256;
                const int s   = idx >> 4;
                const int d4  = (idx & 15) << 2;
                const float4 kv = *(const float4*)(kt + s * KD + d4);
                unsigned short h0 = f2bf(kv.x), h1 = f2bf(kv.y),
                               h2 = f2bf(kv.z), h3 = f2bf(kv.w);
                *(uint2*)&k_s[0][s][d4] = make_uint2(
                    (unsigned)h0 | ((unsigned)h1 << 16),
                    (unsigned)h2 | ((unsigned)h3 << 16));
                *(uint2*)&k_s[1][s][d4] = make_uint2(
                    (unsigned)f2bf(kv.x - bf2f(h0)) | ((unsigned)f2bf(kv.y - bf2f(h1)) << 16),
                    (unsigned)f2bf(kv.z - bf2f(h2)) | ((unsigned)f2bf(kv.w - bf2f(h3)) << 16));
            }
#pragma unroll
            for (int it = 0; it < 2; ++it) {
                const int idx = t + it * 256;
                const int sp  = idx & 31;
                const int d4  = (idx >> 5) << 2;
                const float* v0 = vt + (2 * sp) * KD + d4;
                const float4 a = *(const float4*)v0;
                const float4 b = *(const float4*)(v0 + KD);
#pragma unroll
                for (int j = 0; j < 4; ++j) {
                    *(unsigned*)&v_t[d4 + j][2 * sp] =
                        (unsigned)f2bf((&a.x)[j]) | ((unsigned)f2bf((&b.x)[j]) << 16);
                }
            }
        }
        __syncthreads();

        f32x4 st[4];
#pragma unroll
        for (int sb = 0; sb < 4; ++sb) {
            f32x4 c = (f32x4){0.f, 0.f, 0.f, 0.f};
#pragma unroll
            for (int kk = 0; kk < 2; ++kk) {
                const bf16x8 khi = *(const bf16x8*)&k_s[0][sb * 16 + ln][g * 8 + 32 * kk];
                const bf16x8 klo = *(const bf16x8*)&k_s[1][sb * 16 + ln][g * 8 + 32 * kk];
                c = __builtin_amdgcn_mfma_f32_16x16x32_bf16(klo, qhi[kk], c, 0, 0, 0);
                c = __builtin_amdgcn_mfma_f32_16x16x32_bf16(khi, qlo[kk], c, 0, 0, 0);
                c = __builtin_amdgcn_mfma_f32_16x16x32_bf16(khi, qhi[kk], c, 0, 0, 0);
            }
            st[sb] = c;
        }

        float tm = st[0][0];
#pragma unroll
        for (int sb = 0; sb < 4; ++sb)
#pragma unroll
            for (int r = 0; r < 4; ++r) tm = fmaxf(tm, st[sb][r]);
        tm = fmaxf(tm, __shfl_xor(tm, 16));
        tm = fmaxf(tm, __shfl_xor(tm, 32));

        const float m_new  = fmaxf(m_run, tm);
        const float scalef = __expf(m_run - m_new);
        m_run = m_new;

        float rs = 0.f;
#pragma unroll
        for (int sb = 0; sb < 4; ++sb) {
            const float p0 = __expf(st[sb][0] - m_new);
            const float p1 = __expf(st[sb][1] - m_new);
            const float p2 = __expf(st[sb][2] - m_new);
            const float p3 = __expf(st[sb][3] - m_new);
            rs += (p0 + p1) + (p2 + p3);
            *(uint2*)&p_s[w][ln][sb * 16 + g * 4] =
                make_uint2(pk2(p0, p1), pk2(p2, p3));
        }
        rs += __shfl_xor(rs, 16);
        rs += __shfl_xor(rs, 32);
        l_run = l_run * scalef + rs;

#pragma unroll
        for (int r = 0; r < 4; ++r) {
            const float sr = __shfl(scalef, 4 * g + r);
#pragma unroll
            for (int db = 0; db < 4; ++db) acc[db][r] *= sr;
        }

        bf16x8 pa[2];
#pragma unroll
        for (int kk = 0; kk < 2; ++kk)
            pa[kk] = *(const bf16x8*)&p_s[w][ln][g * 8 + 32 * kk];
#pragma unroll
        for (int db = 0; db < 4; ++db) {
            f32x4 c = acc[db];
#pragma unroll
            for (int kk = 0; kk < 2; ++kk) {
                const bf16x8 vb = *(const bf16x8*)&v_t[ln + 16 * db][g * 8 + 32 * kk];
                c = __builtin_amdgcn_mfma_f32_16x16x32_bf16(pa[kk], vb, c, 0, 0, 0);
            }
            acc[db] = c;
        }
    }

    const float invl = 1.0f / l_run;
    const int b = bh >> 3, h = bh & 7;
#pragma unroll
    for (int r = 0; r < 4; ++r) {
        const float iv = __shfl(invl, 4 * g + r);
        float* orow = out + ((size_t)(b * SEQ + q0 + 4 * g + r) * EMB) + h * KD + ln;
#pragma unroll
        for (int db = 0; db < 4; ++db) orow[16 * db] = acc[db][r] * iv;
    }
}

template <int TRANSQ>
__global__ __launch_bounds__(256) void proj_mfma_kernel(const float* __restrict__ in,
                                                        const float* __restrict__ W,
                                                        float* __restrict__ out) {
    __shared__ unsigned short x_s[2][64][72];
    __shared__ unsigned short w_t[2][64][72];

    const int t  = threadIdx.x;
    const int w  = t >> 6;
    const int l  = t & 63;
    const int g  = l >> 4;
    const int ln = l & 15;

    const int row0 = blockIdx.x * 64;
    const int n0   = blockIdx.y * 64;

    f32x4 acc[4];
#pragma unroll
    for (int cb = 0; cb < 4; ++cb) acc[cb] = (f32x4){0.f, 0.f, 0.f, 0.f};

    for (int ch = 0; ch < EMB / 64; ++ch) {
        __syncthreads();
#pragma unroll
        for (int it = 0; it < 4; ++it) {
            const int idx = t + it * 256;
            const int s   = idx >> 4;
            const int d4  = (idx & 15) << 2;
            const float4 xv = *(const float4*)(in + (size_t)(row0 + s) * EMB + ch * 64 + d4);
            const unsigned short h0 = f2bf(xv.x), h1 = f2bf(xv.y),
                                 h2 = f2bf(xv.z), h3 = f2bf(xv.w);
            *(uint2*)&x_s[0][s][d4] = make_uint2(
                (unsigned)h0 | ((unsigned)h1 << 16),
                (unsigned)h2 | ((unsigned)h3 << 16));
            *(uint2*)&x_s[1][s][d4] = make_uint2(
                (unsigned)f2bf(xv.x - bf2f(h0)) | ((unsigned)f2bf(xv.y - bf2f(h1)) << 16),
                (unsigned)f2bf(xv.z - bf2f(h2)) | ((unsigned)f2bf(xv.w - bf2f(h3)) << 16));
        }
#pragma unroll
        for (int it = 0; it < 2; ++it) {
            const int idx = t + it * 256;
            const int sp  = idx & 31;
            const int c4  = (idx >> 5) << 2;
            const float* wrow = W + (size_t)(ch * 64 + 2 * sp) * EMB + n0 + c4;
            const float4 a = *(const float4*)wrow;
            const float4 b = *(const float4*)(wrow + EMB);
#pragma unroll
            for (int j = 0; j < 4; ++j) {
                const float aj = (&a.x)[j], bj = (&b.x)[j];
                const unsigned short ah = f2bf(aj), bh = f2bf(bj);
                *(unsigned*)&w_t[0][c4 + j][2 * sp] =
                    (unsigned)ah | ((unsigned)bh << 16);
                *(unsigned*)&w_t[1][c4 + j][2 * sp] =
                    (unsigned)f2bf(aj - bf2f(ah)) | ((unsigned)f2bf(bj - bf2f(bh)) << 16);
            }
        }
        __syncthreads();

        bf16x8 ah[2], al[2];
#pragma unroll
        for (int kk = 0; kk < 2; ++kk) {
            ah[kk] = *(const bf16x8*)&x_s[0][w * 16 + ln][g * 8 + 32 * kk];
            al[kk] = *(const bf16x8*)&x_s[1][w * 16 + ln][g * 8 + 32 * kk];
        }
#pragma unroll
        for (int cb = 0; cb < 4; ++cb) {
            f32x4 c = acc[cb];
#pragma unroll
            for (int kk = 0; kk < 2; ++kk) {
                const bf16x8 bh = *(const bf16x8*)&w_t[0][cb * 16 + ln][g * 8 + 32 * kk];
                const bf16x8 bl = *(const bf16x8*)&w_t[1][cb * 16 + ln][g * 8 + 32 * kk];
                c = __builtin_amdgcn_mfma_f32_16x16x32_bf16(al[kk], bh, c, 0, 0, 0);
                c = __builtin_amdgcn_mfma_f32_16x16x32_bf16(ah[kk], bl, c, 0, 0, 0);
                c = __builtin_amdgcn_mfma_f32_16x16x32_bf16(ah[kk], bh, c, 0, 0, 0);
            }
            acc[cb] = c;
        }
    }

#pragma unroll
    for (int cb = 0; cb < 4; ++cb) {
#pragma unroll
        for (int r = 0; r < 4; ++r) {
            const int row = row0 + w * 16 + 4 * g + r;
            const int col = n0 + cb * 16 + ln;
            if (TRANSQ) {
                const int b = row >> 11, s = row & 2047;
                const int h = col >> 6, k = col & 63;
                out[((size_t)(b * HEADS + h) * SEQ + s) * KD + k] = acc[cb][r];
            } else {
                out[(size_t)row * EMB + col] = acc[cb][r];
            }
        }
    }
}

__global__ __launch_bounds__(256) void proj_fp32_kernel(const float* __restrict__ in,
                                                        const float* __restrict__ W,
                                                        float* __restrict__ out) {
    __shared__ float x_s[8][EMB];
    const int block_row = blockIdx.x * 8;

    const float4* in4 = (const float4*)(in + (size_t)block_row * EMB);
    float4* xs4 = (float4*)(&x_s[0][0]);
    for (int i = threadIdx.x; i < 8 * EMB / 4; i += 256) xs4[i] = in4[i];
    __syncthreads();

    const int n  = (threadIdx.x & 127) * 4;
    const int rg = threadIdx.x >> 7;

    float acc[4][4] = {};
    for (int e = 0; e < EMB; ++e) {
        const float4 w4 = *(const float4*)(W + (size_t)e * EMB + n);
#pragma unroll
        for (int rr = 0; rr < 4; ++rr) {
            const float xv = x_s[rg + rr * 2][e];
            acc[rr][0] += xv * w4.x;
            acc[rr][1] += xv * w4.y;
            acc[rr][2] += xv * w4.z;
            acc[rr][3] += xv * w4.w;
        }
    }
#pragma unroll
    for (int rr = 0; rr < 4; ++rr) {
        const int row = block_row + rg + rr * 2;
        float4 o;
        o.x = acc[rr][0]; o.y = acc[rr][1]; o.z = acc[rr][2]; o.w = acc[rr][3];
        *(float4*)(out + (size_t)row * EMB + n) = o;
    }
}

// ===========================================================================
extern "C" void kernel_launch(void* const* d_in, const int* in_sizes, int n_in,
                              void* d_out, int out_size, void* d_ws, size_t ws_size,
                              hipStream_t stream) {
    const float* x  = (const float*)d_in[0];
    const float* ks = (const float*)d_in[1];
    const float* vs = (const float*)d_in[2];
    const float* wq = (const float*)d_in[3];
    const float* wo = (const float*)d_in[4];
    float* out = (float*)d_out;

    const int M = BATCH * SEQ;  // 8192

    // ---- tier A layout (byte offsets) ----
    const size_t XIMG_OFF = 0;                              // 16,777,216
    const size_t WQ_OFF   = 16777216;                       //  1,048,576
    const size_t WO_OFF   = 17825792;                       //    524,288
    const size_t KIMG_OFF = 18350080;                       // 16,777,216
    const size_t VIMG_OFF = 35127296;                       //  8,388,608
    const size_t QHI_OFF  = 43515904;                       //  8,388,608
    const size_t QLO_OFF  = 51904512;                       //  8,388,608
    const size_t CTX_OFF  = 60293120;                       //  8,388,608
    const size_t TIER_A   = 68681728;

    if (ws_size >= TIER_A) {
        unsigned short* ximg  = (unsigned short*)((char*)d_ws + XIMG_OFF);
        unsigned short* wqimg = (unsigned short*)((char*)d_ws + WQ_OFF);
        unsigned short* woimg = (unsigned short*)((char*)d_ws + WO_OFF);
        unsigned short* kimg  = (unsigned short*)((char*)d_ws + KIMG_OFF);
        unsigned short* vimg  = (unsigned short*)((char*)d_ws + VIMG_OFF);
        unsigned short* qhi   = (unsigned short*)((char*)d_ws + QHI_OFF);
        unsigned short* qlo   = (unsigned short*)((char*)d_ws + QLO_OFF);
        unsigned short* ctx   = (unsigned short*)((char*)d_ws + CTX_OFF);

        prep_all_kernel<<<dim3(3200), dim3(256), 0, stream>>>(
            x, wq, wo, ks, vs, ximg, wqimg, woimg, kimg, vimg);
        proj_q_kernel<<<dim3(M / 64, HEADS), dim3(256), 0, stream>>>(ximg, wqimg, qhi, qlo);
        attn4_kernel<<<dim3(SEQ / 64, BATCH * HEADS), dim3(256), 0, stream>>>(
            qhi, qlo, kimg, vimg, ctx);
        proj_o_kernel<<<dim3(M / 64, EMB / 64), dim3(256), 0, stream>>>(ctx, woimg, out);
        return;
    }

    // ---- tier B: round-8 path ----
    const size_t QBYTES  = (size_t)BATCH * HEADS * SEQ * KD * 4;
    const size_t CBYTES  = (size_t)BATCH * SEQ * EMB * 4;
    const size_t KIBYTES = (size_t)BATCH * HEADS * SEQ * KD * 2 * 2;
    const size_t VIBYTES = (size_t)BATCH * HEADS * SEQ * KD * 2;

    float* Q = (float*)d_ws;
    const bool mid_ws  = ws_size >= QBYTES + CBYTES;
    const bool full_ws = ws_size >= QBYTES + CBYTES + KIBYTES + VIBYTES;
    float* ctxf = mid_ws ? (float*)((char*)d_ws + QBYTES) : out;
    unsigned short* kimg = (unsigned short*)((char*)d_ws + QBYTES + CBYTES);
    unsigned short* vimg = (unsigned short*)((char*)d_ws + QBYTES + CBYTES + KIBYTES);

    proj_mfma_kernel<1><<<dim3(M / 64, EMB / 64), dim3(256), 0, stream>>>(x, wq, Q);

    if (full_ws) {
        prep_k_kernel<<<dim3(BATCH * HEADS * 32), dim3(256), 0, stream>>>(ks, kimg);
        prep_v_kernel<<<dim3(BATCH * HEADS * 32), dim3(256), 0, stream>>>(vs, vimg);
        attn3_kernel<1><<<dim3(SEQ / 64, BATCH * HEADS), dim3(256), 0, stream>>>(
            Q, ks, vs, kimg, vimg, ctxf);
    } else {
        attn3_kernel<0><<<dim3(SEQ / 64, BATCH * HEADS), dim3(256), 0, stream>>>(
            Q, ks, vs, nullptr, nullptr, ctxf);
    }

    if (mid_ws) {
        proj_mfma_kernel<0><<<dim3(M / 64, EMB / 64), dim3(256), 0, stream>>>(ctxf, wo, out);
    } else {
        proj_fp32_kernel<<<dim3(M / 8), dim3(256), 0, stream>>>(ctxf, wo, out);
    }
}

// Round 10
// 243.245 us; speedup vs baseline: 1.3266x; 1.0085x over previous
//
#include <hip/hip_runtime.h>
#include <hip/hip_bf16.h>

#define EMB 512
#define HEADS 8
#define KD 64
#define SEQ 2048
#define BATCH 4

typedef __attribute__((ext_vector_type(8))) short bf16x8;
typedef __attribute__((ext_vector_type(4))) float f32x4;
typedef __attribute__((ext_vector_type(16))) float f32x16;

__device__ __forceinline__ unsigned short f2bf(float x) {
    union { float f; unsigned u; } v; v.f = x;
    unsigned r = v.u + 0x7fff + ((v.u >> 16) & 1);   // RNE
    return (unsigned short)(r >> 16);
}
__device__ __forceinline__ float bf2f(unsigned short b) {
    union { unsigned u; float f; } v; v.u = ((unsigned)b) << 16;
    return v.f;
}
__device__ __forceinline__ unsigned pk2(float a, float b) {  // packed bf16 pair (RNE)
    __hip_bfloat162 h = __float22bfloat162_rn(float2{a, b});
    unsigned u; __builtin_memcpy(&u, &h, 4); return u;
}

// ===========================================================================
//                                TIER A
// ===========================================================================
// Fused prep: x -> hi/lo tile images; Wq -> W^T hi/lo; Wo -> W^T bf16;
// K -> hi/lo images; V -> V^T images. Grid 3200 blocks.
// ---------------------------------------------------------------------------
__global__ __launch_bounds__(256) void prep_all_kernel(
    const float* __restrict__ x,  const float* __restrict__ wq,
    const float* __restrict__ wo, const float* __restrict__ K,
    const float* __restrict__ V,
    unsigned short* __restrict__ ximg, unsigned short* __restrict__ wqimg,
    unsigned short* __restrict__ woimg, unsigned short* __restrict__ kimg,
    unsigned short* __restrict__ vimg) {
    const int bid = blockIdx.x;
    const int t   = threadIdx.x;

    if (bid < 1024) {
        const int rb = bid >> 3, ch = bid & 7;
        const float* src = x + (size_t)rb * 64 * EMB + ch * 64;
        unsigned short* dhi = ximg + (size_t)bid * 8192;
        unsigned short* dlo = dhi + 4096;
#pragma unroll
        for (int it = 0; it < 4; ++it) {
            const int idx = t + it * 256;
            const int row = idx >> 4, c4 = (idx & 15) << 2;
            const float4 v = *(const float4*)(src + (size_t)row * EMB + c4);
            const unsigned short h0 = f2bf(v.x), h1 = f2bf(v.y),
                                 h2 = f2bf(v.z), h3 = f2bf(v.w);
            *(uint2*)&dhi[row * 64 + c4] = make_uint2(
                (unsigned)h0 | ((unsigned)h1 << 16),
                (unsigned)h2 | ((unsigned)h3 << 16));
            *(uint2*)&dlo[row * 64 + c4] = make_uint2(
                (unsigned)f2bf(v.x - bf2f(h0)) | ((unsigned)f2bf(v.y - bf2f(h1)) << 16),
                (unsigned)f2bf(v.z - bf2f(h2)) | ((unsigned)f2bf(v.w - bf2f(h3)) << 16));
        }
    } else if (bid < 1152) {
        int widx = bid - 1024;
        const bool isq = widx < 64;
        if (!isq) widx -= 64;
        const int nb = widx >> 3, ch = widx & 7;
        const float* src = (isq ? wq : wo) + (size_t)(ch * 64) * EMB + nb * 64;
        unsigned short* dhi = isq ? (wqimg + (size_t)widx * 8192)
                                  : (woimg + (size_t)widx * 4096);
        unsigned short* dlo = dhi + 4096;
#pragma unroll
        for (int it = 0; it < 2; ++it) {
            const int idx = t + it * 256;
            const int sp  = idx & 31;
            const int c4  = (idx >> 5) << 2;
            const float* r0 = src + (size_t)(2 * sp) * EMB + c4;
            const float4 a = *(const float4*)r0;
            const float4 b = *(const float4*)(r0 + EMB);
#pragma unroll
            for (int j = 0; j < 4; ++j) {
                const float aj = (&a.x)[j], bj = (&b.x)[j];
                const unsigned short ah = f2bf(aj), bh = f2bf(bj);
                *(unsigned*)&dhi[(c4 + j) * 64 + 2 * sp] =
                    (unsigned)ah | ((unsigned)bh << 16);
                if (isq)
                    *(unsigned*)&dlo[(c4 + j) * 64 + 2 * sp] =
                        (unsigned)f2bf(aj - bf2f(ah)) | ((unsigned)f2bf(bj - bf2f(bh)) << 16);
            }
        }
    } else if (bid < 2176) {
        const int kt = bid - 1152;
        const float4* src = (const float4*)(K + (size_t)kt * 4096);
        unsigned short* dhi = kimg + (size_t)kt * 8192;
        unsigned short* dlo = dhi + 4096;
#pragma unroll
        for (int it = 0; it < 4; ++it) {
            const int idx = t + it * 256;
            const float4 v = src[idx];
            const unsigned short h0 = f2bf(v.x), h1 = f2bf(v.y),
                                 h2 = f2bf(v.z), h3 = f2bf(v.w);
            *(uint2*)&dhi[idx * 4] = make_uint2(
                (unsigned)h0 | ((unsigned)h1 << 16),
                (unsigned)h2 | ((unsigned)h3 << 16));
            *(uint2*)&dlo[idx * 4] = make_uint2(
                (unsigned)f2bf(v.x - bf2f(h0)) | ((unsigned)f2bf(v.y - bf2f(h1)) << 16),
                (unsigned)f2bf(v.z - bf2f(h2)) | ((unsigned)f2bf(v.w - bf2f(h3)) << 16));
        }
    } else {
        const int vt = bid - 2176;
        const float* src = V + (size_t)vt * 4096;
        unsigned short* dst = vimg + (size_t)vt * 4096;
#pragma unroll
        for (int it = 0; it < 2; ++it) {
            const int idx = t + it * 256;
            const int sp  = idx & 31;
            const int d4  = (idx >> 5) << 2;
            const float4 a = *(const float4*)(src + (2 * sp) * KD + d4);
            const float4 b = *(const float4*)(src + (2 * sp + 1) * KD + d4);
#pragma unroll
            for (int j = 0; j < 4; ++j) {
                *(unsigned*)&dst[(d4 + j) * 64 + 2 * sp] =
                    (unsigned)f2bf((&a.x)[j]) | ((unsigned)f2bf((&b.x)[j]) << 16);
            }
        }
    }
}

// ---------------------------------------------------------------------------
// Q projection from images: pure-copy staging, 3-term split-bf16 MFMA.
// Writes Q (x0.125) as bf16 hi/lo images [B,H,S,64].
// ---------------------------------------------------------------------------
__global__ __launch_bounds__(256) void proj_q_kernel(
    const unsigned short* __restrict__ ximg,
    const unsigned short* __restrict__ wqimg,
    unsigned short* __restrict__ qhi_img,
    unsigned short* __restrict__ qlo_img) {
    __shared__ unsigned short x_s[2][64][72];
    __shared__ unsigned short w_t[2][64][72];

    const int t  = threadIdx.x;
    const int w  = t >> 6;
    const int l  = t & 63;
    const int g  = l >> 4;
    const int ln = l & 15;

    const int rb = blockIdx.x;
    const int nb = blockIdx.y;

    f32x4 acc[4];
#pragma unroll
    for (int cb = 0; cb < 4; ++cb) acc[cb] = (f32x4){0.f, 0.f, 0.f, 0.f};

    for (int ch = 0; ch < 8; ++ch) {
        __syncthreads();
        const uint4* xs = (const uint4*)(ximg + (size_t)(rb * 8 + ch) * 8192);
        const uint4* ws = (const uint4*)(wqimg + (size_t)(nb * 8 + ch) * 8192);
#pragma unroll
        for (int it = 0; it < 4; ++it) {
            const int idx = t + it * 256;
            const int hl  = idx >> 9;
            const int rem = idx & 511;
            *(uint4*)&x_s[hl][rem >> 3][(rem & 7) * 8] = xs[idx];
            *(uint4*)&w_t[hl][rem >> 3][(rem & 7) * 8] = ws[idx];
        }
        __syncthreads();

        bf16x8 ah[2], al[2];
#pragma unroll
        for (int kk = 0; kk < 2; ++kk) {
            ah[kk] = *(const bf16x8*)&x_s[0][w * 16 + ln][g * 8 + 32 * kk];
            al[kk] = *(const bf16x8*)&x_s[1][w * 16 + ln][g * 8 + 32 * kk];
        }
#pragma unroll
        for (int cb = 0; cb < 4; ++cb) {
            f32x4 c = acc[cb];
#pragma unroll
            for (int kk = 0; kk < 2; ++kk) {
                const bf16x8 bh = *(const bf16x8*)&w_t[0][cb * 16 + ln][g * 8 + 32 * kk];
                const bf16x8 bl = *(const bf16x8*)&w_t[1][cb * 16 + ln][g * 8 + 32 * kk];
                c = __builtin_amdgcn_mfma_f32_16x16x32_bf16(al[kk], bh, c, 0, 0, 0);
                c = __builtin_amdgcn_mfma_f32_16x16x32_bf16(ah[kk], bl, c, 0, 0, 0);
                c = __builtin_amdgcn_mfma_f32_16x16x32_bf16(ah[kk], bh, c, 0, 0, 0);
            }
            acc[cb] = c;
        }
    }

#pragma unroll
    for (int cb = 0; cb < 4; ++cb) {
#pragma unroll
        for (int r = 0; r < 4; ++r) {
            const int row = rb * 64 + w * 16 + 4 * g + r;
            const int k   = cb * 16 + ln;
            const float v = acc[cb][r] * 0.125f;
            const unsigned short hi = f2bf(v);
            const unsigned short lo = f2bf(v - bf2f(hi));
            const size_t off = ((size_t)((row >> 11) * HEADS + nb) * SEQ + (row & 2047)) * KD + k;
            qhi_img[off] = hi;
            qlo_img[off] = lo;
        }
    }
}

// ---------------------------------------------------------------------------
// Out projection from ctx image (bf16) + Wo image (bf16): 1-term MFMA.
// ---------------------------------------------------------------------------
__global__ __launch_bounds__(256) void proj_o_kernel(
    const unsigned short* __restrict__ ctximg,
    const unsigned short* __restrict__ woimg,
    float* __restrict__ out) {
    __shared__ unsigned short x_s[64][72];
    __shared__ unsigned short w_t[64][72];

    const int t  = threadIdx.x;
    const int w  = t >> 6;
    const int l  = t & 63;
    const int g  = l >> 4;
    const int ln = l & 15;

    const int rb = blockIdx.x;
    const int nb = blockIdx.y;

    f32x4 acc[4];
#pragma unroll
    for (int cb = 0; cb < 4; ++cb) acc[cb] = (f32x4){0.f, 0.f, 0.f, 0.f};

    for (int ch = 0; ch < 8; ++ch) {
        __syncthreads();
        const uint4* xs = (const uint4*)(ctximg + (size_t)(rb * 8 + ch) * 4096);
        const uint4* ws = (const uint4*)(woimg + (size_t)(nb * 8 + ch) * 4096);
#pragma unroll
        for (int it = 0; it < 2; ++it) {
            const int idx = t + it * 256;
            *(uint4*)&x_s[idx >> 3][(idx & 7) * 8] = xs[idx];
            *(uint4*)&w_t[idx >> 3][(idx & 7) * 8] = ws[idx];
        }
        __syncthreads();

        bf16x8 ah[2];
#pragma unroll
        for (int kk = 0; kk < 2; ++kk)
            ah[kk] = *(const bf16x8*)&x_s[w * 16 + ln][g * 8 + 32 * kk];
#pragma unroll
        for (int cb = 0; cb < 4; ++cb) {
            f32x4 c = acc[cb];
#pragma unroll
            for (int kk = 0; kk < 2; ++kk) {
                const bf16x8 bh = *(const bf16x8*)&w_t[cb * 16 + ln][g * 8 + 32 * kk];
                c = __builtin_amdgcn_mfma_f32_16x16x32_bf16(ah[kk], bh, c, 0, 0, 0);
            }
            acc[cb] = c;
        }
    }

#pragma unroll
    for (int cb = 0; cb < 4; ++cb) {
#pragma unroll
        for (int r = 0; r < 4; ++r) {
            const int row = rb * 64 + w * 16 + 4 * g + r;
            const int col = nb * 64 + cb * 16 + ln;
            out[(size_t)row * EMB + col] = acc[cb][r];
        }
    }
}

// ---------------------------------------------------------------------------
// attn5: 32x32x16 MFMA flash attention.
// 4 waves = (qh, sh) quadrants of the 64q x 64s tile.
// Scores: S^T[32s][32q] = K·Q^T (3-term split). C layout: col=lane&31=q,
// row=(reg&3)+8*(reg>>2)+4*(lane>>5)=s -> softmax is in-lane + 1 shfl_xor(32).
// Each wave keeps independent (m,l,acc[32q x 64d]) over its s-half stream;
// partners flash-merge once in the epilogue via LDS. Defer-max (THR=8).
// ---------------------------------------------------------------------------
__global__ __launch_bounds__(256) void attn5_kernel(
    const unsigned short* __restrict__ qhi_img,
    const unsigned short* __restrict__ qlo_img,
    const unsigned short* __restrict__ kimg,
    const unsigned short* __restrict__ vimg,
    unsigned short* __restrict__ ctximg) {
    constexpr int LDK = 72;
    constexpr int LDP = 40;   // 80B row stride -> 5 slots, conflict-optimal

    __shared__ unsigned short k_s[2][64][LDK];     // 18,432 B
    __shared__ unsigned short v_t[64][LDK];        //  9,216 B
    __shared__ unsigned short p_s[4][32][LDP];     // 10,240 B
    __shared__ float m_arr[2][2][32], l_arr[2][2][32];  // 1,024 B

    const int t   = threadIdx.x;
    const int w   = t >> 6;
    const int l   = t & 63;
    const int qh  = w >> 1;
    const int sh  = w & 1;
    const int q32 = l & 31;     // q (scores C col, PV A row, B col)
    const int h   = l >> 5;

    const int bh = blockIdx.y;
    const int q0 = blockIdx.x * 64;

    // Q fragments (B-operand): col q=q32 (+qh*32), k=d = 16*ks + 8*h + j
    bf16x8 qhi[4], qlo[4];
    {
        const size_t qoff = ((size_t)bh * SEQ + q0 + qh * 32 + q32) * KD + 8 * h;
#pragma unroll
        for (int ks = 0; ks < 4; ++ks) {
            qhi[ks] = *(const bf16x8*)&qhi_img[qoff + 16 * ks];
            qlo[ks] = *(const bf16x8*)&qlo_img[qoff + 16 * ks];
        }
    }

    f32x16 acc0, acc1;   // PV C: rows q (reg pattern), cols d = db*32 + q32
#pragma unroll
    for (int i = 0; i < 16; ++i) { acc0[i] = 0.f; acc1[i] = 0.f; }
    float m_run = -1e30f, l_run = 0.f;

    for (int tile = 0; tile < SEQ / 64; ++tile) {
        __syncthreads();

        // ---- stage K (hi/lo) + V^T by pure uint4 copy ----
        const uint4* ksrc = (const uint4*)(kimg + (size_t)(bh * 32 + tile) * 8192);
#pragma unroll
        for (int it = 0; it < 4; ++it) {
            const int idx = t + it * 256;
            const int hl  = idx >> 9;
            const int rem = idx & 511;
            *(uint4*)&k_s[hl][rem >> 3][(rem & 7) * 8] = ksrc[idx];
        }
        const uint4* vsrc = (const uint4*)(vimg + (size_t)(bh * 32 + tile) * 4096);
#pragma unroll
        for (int it = 0; it < 2; ++it) {
            const int idx = t + it * 256;
            *(uint4*)&v_t[idx >> 3][(idx & 7) * 8] = vsrc[idx];
        }
        __syncthreads();

        // ---- scores: S^T[32s][32q] = K·Q^T, 3-term split ----
        f32x16 st;
#pragma unroll
        for (int i = 0; i < 16; ++i) st[i] = 0.f;
        const int srow = sh * 32 + q32;   // A row: s = q32 within this half
#pragma unroll
        for (int ks = 0; ks < 4; ++ks) {
            const bf16x8 khi = *(const bf16x8*)&k_s[0][srow][16 * ks + 8 * h];
            const bf16x8 klo = *(const bf16x8*)&k_s[1][srow][16 * ks + 8 * h];
            st = __builtin_amdgcn_mfma_f32_32x32x16_bf16(klo, qhi[ks], st, 0, 0, 0);
            st = __builtin_amdgcn_mfma_f32_32x32x16_bf16(khi, qlo[ks], st, 0, 0, 0);
            st = __builtin_amdgcn_mfma_f32_32x32x16_bf16(khi, qhi[ks], st, 0, 0, 0);
        }

        // ---- online softmax for q=q32 over this wave's 32 s ----
        float tm = st[0];
#pragma unroll
        for (int i = 1; i < 16; ++i) tm = fmaxf(tm, st[i]);
        tm = fmaxf(tm, __shfl_xor(tm, 32));

        if (__any(tm > m_run + 8.0f)) {      // defer-max: rescale only on growth
            const float m_new = fmaxf(m_run, tm);
            const float sc = __expf(m_run - m_new);
            m_run = m_new;
            l_run *= sc;
#pragma unroll
            for (int r = 0; r < 16; ++r) {
                const int qrow = (r & 3) + 8 * (r >> 2) + 4 * h;
                const float sr = __shfl(sc, qrow);
                acc0[r] *= sr; acc1[r] *= sr;
            }
        }

        float rs = 0.f;
#pragma unroll
        for (int i = 0; i < 8; ++i) {
            const float pa_ = __expf(st[2 * i]     - m_run);
            const float pb_ = __expf(st[2 * i + 1] - m_run);
            rs += pa_ + pb_;
            const int sbase = ((2 * i) & 3) + 8 * (i >> 1) + 4 * h;  // s of reg 2i
            *(unsigned*)&p_s[w][q32][sbase] = pk2(pa_, pb_);
        }
        rs += __shfl_xor(rs, 32);
        l_run += rs;

        // ---- PV: acc[32q x 64d] += P[32q x 32s] · V[32s x 64d] ----
        // (same-wave p_s write->read; compiler inserts lgkmcnt)
#pragma unroll
        for (int ks = 0; ks < 2; ++ks) {
            const bf16x8 pa = *(const bf16x8*)&p_s[w][q32][16 * ks + 8 * h];
            const bf16x8 v0 = *(const bf16x8*)&v_t[q32]     [sh * 32 + 16 * ks + 8 * h];
            const bf16x8 v1 = *(const bf16x8*)&v_t[32 + q32][sh * 32 + 16 * ks + 8 * h];
            acc0 = __builtin_amdgcn_mfma_f32_32x32x16_bf16(pa, v0, acc0, 0, 0, 0);
            acc1 = __builtin_amdgcn_mfma_f32_32x32x16_bf16(pa, v1, acc1, 0, 0, 0);
        }
    }

    // ---- epilogue: flash-merge sh partners, write bf16 ctx tile image ----
    __syncthreads();
    if (l < 32) { m_arr[sh][qh][l] = m_run; l_arr[sh][qh][l] = l_run; }
    __syncthreads();
    const float m_o = m_arr[sh ^ 1][qh][q32];
    const float l_o = l_arr[sh ^ 1][qh][q32];
    const float m_f = fmaxf(m_run, m_o);
    const float a_own = __expf(m_run - m_f);
    const float inv_lf = 1.0f / (a_own * l_run + __expf(m_o - m_f) * l_o);

    float* cmerge = (float*)&k_s[0][0][0];   // 16 KB reuse: [64 q][64 d]
    if (sh == 1) {
#pragma unroll
        for (int r = 0; r < 16; ++r) {
            const int qrow = (r & 3) + 8 * (r >> 2) + 4 * h;
            const float sr = __shfl(a_own, qrow);
            cmerge[(qh * 32 + qrow) * 64 + q32]      = acc0[r] * sr;
            cmerge[(qh * 32 + qrow) * 64 + 32 + q32] = acc1[r] * sr;
        }
    }
    __syncthreads();
    if (sh == 0) {
        const int rb  = (bh >> 3) * 32 + blockIdx.x;
        const int chh = bh & 7;
        unsigned short* cbase = ctximg + ((size_t)rb * 8 + chh) * 4096;
#pragma unroll
        for (int r = 0; r < 16; ++r) {
            const int qrow = (r & 3) + 8 * (r >> 2) + 4 * h;
            const float sr  = __shfl(a_own, qrow);
            const float ivr = __shfl(inv_lf, qrow);
            const float v0 = (acc0[r] * sr + cmerge[(qh * 32 + qrow) * 64 + q32]) * ivr;
            const float v1 = (acc1[r] * sr + cmerge[(qh * 32 + qrow) * 64 + 32 + q32]) * ivr;
            cbase[(qh * 32 + qrow) * 64 + q32]      = f2bf(v0);
            cbase[(qh * 32 + qrow) * 64 + 32 + q32] = f2bf(v1);
        }
    }
}

// ===========================================================================
//                      TIER B (round-8 path, fallback)
// ===========================================================================
__global__ __launch_bounds__(256) void prep_k_kernel(const float* __restrict__ K,
                                                     unsigned short* __restrict__ kimg) {
    const int bt = blockIdx.x;
    const float4* src = (const float4*)(K + (size_t)bt * 4096);
    unsigned short* dhi = kimg + (size_t)bt * 8192;
    unsigned short* dlo = dhi + 4096;
#pragma unroll
    for (int it = 0; it < 4; ++it) {
        const int idx = threadIdx.x + it * 256;
        const float4 v = src[idx];
        const unsigned short h0 = f2bf(v.x), h1 = f2bf(v.y),
                             h2 = f2bf(v.z), h3 = f2bf(v.w);
        *(uint2*)&dhi[idx * 4] = make_uint2(
            (unsigned)h0 | ((unsigned)h1 << 16),
            (unsigned)h2 | ((unsigned)h3 << 16));
        *(uint2*)&dlo[idx * 4] = make_uint2(
            (unsigned)f2bf(v.x - bf2f(h0)) | ((unsigned)f2bf(v.y - bf2f(h1)) << 16),
            (unsigned)f2bf(v.z - bf2f(h2)) | ((unsigned)f2bf(v.w - bf2f(h3)) << 16));
    }
}

__global__ __launch_bounds__(256) void prep_v_kernel(const float* __restrict__ V,
                                                     unsigned short* __restrict__ vimg) {
    const int bt = blockIdx.x;
    const float* src = V + (size_t)bt * 4096;
    unsigned short* dst = vimg + (size_t)bt * 4096;
#pragma unroll
    for (int it = 0; it < 2; ++it) {
        const int idx = threadIdx.x + it * 256;
        const int sp  = idx & 31;
        const int d4  = (idx >> 5) << 2;
        const float4 a = *(const float4*)(src + (2 * sp) * KD + d4);
        const float4 b = *(const float4*)(src + (2 * sp + 1) * KD + d4);
#pragma unroll
        for (int j = 0; j < 4; ++j) {
            *(unsigned*)&dst[(d4 + j) * 64 + 2 * sp] =
                (unsigned)f2bf((&a.x)[j]) | ((unsigned)f2bf((&b.x)[j]) << 16);
        }
    }
}

template <int PREP>
__global__ __launch_bounds__(256) void attn3_kernel(const float* __restrict__ Q,
                                                    const float* __restrict__ Keys,
                                                    const float* __restrict__ Vals,
                                                    const unsigned short* __restrict__ kimg,
                                                    const unsigned short* __restrict__ vimg,
                                                    float* __restrict__ out) {
    constexpr int NT  = 64;
    constexpr int LDK = 72;

    __shared__ unsigned short k_s[2][NT][LDK];
    __shared__ unsigned short v_t[KD][LDK];
    __shared__ unsigned short p_s[4][16][LDK];

    const int t  = threadIdx.x;
    const int w  = t >> 6;
    const int l  = t & 63;
    const int g  = l >> 4;
    const int ln = l & 15;

    const int bh = blockIdx.y;
    const int q0 = blockIdx.x * 64 + w * 16;

    const float* kbase = Keys + (size_t)bh * SEQ * KD;
    const float* vbase = Vals + (size_t)bh * SEQ * KD;
    const float* qptr  = Q + ((size_t)bh * SEQ + q0 + ln) * KD;

    bf16x8 qhi[2], qlo[2];
#pragma unroll
    for (int kk = 0; kk < 2; ++kk) {
        const float* p = qptr + g * 8 + 32 * kk;
#pragma unroll
        for (int j = 0; j < 8; ++j) {
            const float xv = p[j] * 0.125f;
            const unsigned short h = f2bf(xv);
            qhi[kk][j] = (short)h;
            qlo[kk][j] = (short)f2bf(xv - bf2f(h));
        }
    }

    f32x4 acc[4];
#pragma unroll
    for (int db = 0; db < 4; ++db) acc[db] = (f32x4){0.f, 0.f, 0.f, 0.f};
    float m_run = -1e30f, l_run = 0.0f;

    for (int tile = 0; tile < SEQ / NT; ++tile) {
        __syncthreads();

        if (PREP) {
            const uint4* ksrc = (const uint4*)(kimg + (size_t)(bh * 32 + tile) * 8192);
#pragma unroll
            for (int it = 0; it < 4; ++it) {
                const int idx = t + it * 256;
                const int hl  = idx >> 9;
                const int rem = idx & 511;
                *(uint4*)&k_s[hl][rem >> 3][(rem & 7) * 8] = ksrc[idx];
            }
            const uint4* vsrc = (const uint4*)(vimg + (size_t)(bh * 32 + tile) * 4096);
#pragma unroll
            for (int it = 0; it < 2; ++it) {
                const int idx = t + it * 256;
                *(uint4*)&v_t[idx >> 3][(idx & 7) * 8] = vsrc[idx];
            }
        } else {
            const float* kt = kbase + (size_t)tile * NT * KD;
            const float* vt = vbase + (size_t)tile * NT * KD;
#pragma unroll
            for (int it = 0; it < 4; ++it) {
                const int idx = t + it * 256;
                const int s   = idx >> 4;
                const int d4  = (idx & 15) << 2;
                const float4 kv = *(const float4*)(kt + s * KD + d4);
                unsigned short h0 = f2bf(kv.x), h1 = f2bf(kv.y),
                               h2 = f2bf(kv.z), h3 = f2bf(kv.w);
                *(uint2*)&k_s[0][s][d4] = make_uint2(
                    (unsigned)h0 | ((unsigned)h1 << 16),
                    (unsigned)h2 | ((unsigned)h3 << 16));
                *(uint2*)&k_s[1][s][d4] = make_uint2(
                    (unsigned)f2bf(kv.x - bf2f(h0)) | ((unsigned)f2bf(kv.y - bf2f(h1)) << 16),
                    (unsigned)f2bf(kv.z - bf2f(h2)) | ((unsigned)f2bf(kv.w - bf2f(h3)) << 16));
            }
#pragma unroll
            for (int it = 0; it < 2; ++it) {
                const int idx = t + it * 256;
                const int sp  = idx & 31;
                const int d4  = (idx >> 5) << 2;
                const float* v0 = vt + (2 * sp) * KD + d4;
                const float4 a = *(const float4*)v0;
                const float4 b = *(const float4*)(v0 + KD);
#pragma unroll
                for (int j = 0; j < 4; ++j) {
                    *(unsigned*)&v_t[d4 + j][2 * sp] =
                        (unsigned)f2bf((&a.x)[j]) | ((unsigned)f2bf((&b.x)[j]) << 16);
                }
            }
        }
        __syncthreads();

        f32x4 st[4];
#pragma unroll
        for (int sb = 0; sb < 4; ++sb) {
            f32x4 c = (f32x4){0.f, 0.f, 0.f, 0.f};
#pragma unroll
            for (int kk = 0; kk < 2; ++kk) {
                const bf16x8 khi = *(const bf16x8*)&k_s[0][sb * 16 + ln][g * 8 + 32 * kk];
                const bf16x8 klo = *(const bf16x8*)&k_s[1][sb * 16 + ln][g * 8 + 32 * kk];
                c = __builtin_amdgcn_mfma_f32_16x16x32_bf16(klo, qhi[kk], c, 0, 0, 0);
                c = __builtin_amdgcn_mfma_f32_16x16x32_bf16(khi, qlo[kk], c, 0, 0, 0);
                c = __builtin_amdgcn_mfma_f32_16x16x32_bf16(khi, qhi[kk], c, 0, 0, 0);
            }
            st[sb] = c;
        }

        float tm = st[0][0];
#pragma unroll
        for (int sb = 0; sb < 4; ++sb)
#pragma unroll
            for (int r = 0; r < 4; ++r) tm = fmaxf(tm, st[sb][r]);
        tm = fmaxf(tm, __shfl_xor(tm, 16));
        tm = fmaxf(tm, __shfl_xor(tm, 32));

        const float m_new  = fmaxf(m_run, tm);
        const float scalef = __expf(m_run - m_new);
        m_run = m_new;

        float rs = 0.f;
#pragma unroll
        for (int sb = 0; sb < 4; ++sb) {
            const float p0 = __expf(st[sb][0] - m_new);
            const float p1 = __expf(st[sb][1] - m_new);
            const float p2 = __expf(st[sb][2] - m_new);
            const float p3 = __expf(st[sb][3] - m_new);
            rs += (p0 + p1) + (p2 + p3);
            *(uint2*)&p_s[w][ln][sb * 16 + g * 4] =
                make_uint2(pk2(p0, p1), pk2(p2, p3));
        }
        rs += __shfl_xor(rs, 16);
        rs += __shfl_xor(rs, 32);
        l_run = l_run * scalef + rs;

#pragma unroll
        for (int r = 0; r < 4; ++r) {
            const float sr = __shfl(scalef, 4 * g + r);
#pragma unroll
            for (int db = 0; db < 4; ++db) acc[db][r] *= sr;
        }

        bf16x8 pa[2];
#pragma unroll
        for (int kk = 0; kk < 2; ++kk)
            pa[kk] = *(const bf16x8*)&p_s[w][ln][g * 8 + 32 * kk];
#pragma unroll
        for (int db = 0; db < 4; ++db) {
            f32x4 c = acc[db];
#pragma unroll
            for (int kk = 0; kk < 2; ++kk) {
                const bf16x8 vb = *(const bf16x8*)&v_t[ln + 16 * db][g * 8 + 32 * kk];
                c = __builtin_amdgcn_mfma_f32_16x16x32_bf16(pa[kk], vb, c, 0, 0, 0);
            }
            acc[db] = c;
        }
    }

    const float invl = 1.0f / l_run;
    const int b = bh >> 3, h = bh & 7;
#pragma unroll
    for (int r = 0; r < 4; ++r) {
        const float iv = __shfl(invl, 4 * g + r);
        float* orow = out + ((size_t)(b * SEQ + q0 + 4 * g + r) * EMB) + h * KD + ln;
#pragma unroll
        for (int db = 0; db < 4; ++db) orow[16 * db] = acc[db][r] * iv;
    }
}

template <int TRANSQ>
__global__ __launch_bounds__(256) void proj_mfma_kernel(const float* __restrict__ in,
                                                        const float* __restrict__ W,
                                                        float* __restrict__ out) {
    __shared__ unsigned short x_s[2][64][72];
    __shared__ unsigned short w_t[2][64][72];

    const int t  = threadIdx.x;
    const int w  = t >> 6;
    const int l  = t & 63;
    const int g  = l >> 4;
    const int ln = l & 15;

    const int row0 = blockIdx.x * 64;
    const int n0   = blockIdx.y * 64;

    f32x4 acc[4];
#pragma unroll
    for (int cb = 0; cb < 4; ++cb) acc[cb] = (f32x4){0.f, 0.f, 0.f, 0.f};

    for (int ch = 0; ch < EMB / 64; ++ch) {
        __syncthreads();
#pragma unroll
        for (int it = 0; it < 4; ++it) {
            const int idx = t + it * 256;
            const int s   = idx >> 4;
            const int d4  = (idx & 15) << 2;
            const float4 xv = *(const float4*)(in + (size_t)(row0 + s) * EMB + ch * 64 + d4);
            const unsigned short h0 = f2bf(xv.x), h1 = f2bf(xv.y),
                                 h2 = f2bf(xv.z), h3 = f2bf(xv.w);
            *(uint2*)&x_s[0][s][d4] = make_uint2(
                (unsigned)h0 | ((unsigned)h1 << 16),
                (unsigned)h2 | ((unsigned)h3 << 16));
            *(uint2*)&x_s[1][s][d4] = make_uint2(
                (unsigned)f2bf(xv.x - bf2f(h0)) | ((unsigned)f2bf(xv.y - bf2f(h1)) << 16),
                (unsigned)f2bf(xv.z - bf2f(h2)) | ((unsigned)f2bf(xv.w - bf2f(h3)) << 16));
        }
#pragma unroll
        for (int it = 0; it < 2; ++it) {
            const int idx = t + it * 256;
            const int sp  = idx & 31;
            const int c4  = (idx >> 5) << 2;
            const float* wrow = W + (size_t)(ch * 64 + 2 * sp) * EMB + n0 + c4;
            const float4 a = *(const float4*)wrow;
            const float4 b = *(const float4*)(wrow + EMB);
#pragma unroll
            for (int j = 0; j < 4; ++j) {
                const float aj = (&a.x)[j], bj = (&b.x)[j];
                const unsigned short ah = f2bf(aj), bh = f2bf(bj);
                *(unsigned*)&w_t[0][c4 + j][2 * sp] =
                    (unsigned)ah | ((unsigned)bh << 16);
                *(unsigned*)&w_t[1][c4 + j][2 * sp] =
                    (unsigned)f2bf(aj - bf2f(ah)) | ((unsigned)f2bf(bj - bf2f(bh)) << 16);
            }
        }
        __syncthreads();

        bf16x8 ah[2], al[2];
#pragma unroll
        for (int kk = 0; kk < 2; ++kk) {
            ah[kk] = *(const bf16x8*)&x_s[0][w * 16 + ln][g * 8 + 32 * kk];
            al[kk] = *(const bf16x8*)&x_s[1][w * 16 + ln][g * 8 + 32 * kk];
        }
#pragma unroll
        for (int cb = 0; cb < 4; ++cb) {
            f32x4 c = acc[cb];
#pragma unroll
            for (int kk = 0; kk < 2; ++kk) {
                const bf16x8 bh = *(const bf16x8*)&w_t[0][cb * 16 + ln][g * 8 + 32 * kk];
                const bf16x8 bl = *(const bf16x8*)&w_t[1][cb * 16 + ln][g * 8 + 32 * kk];
                c = __builtin_amdgcn_mfma_f32_16x16x32_bf16(al[kk], bh, c, 0, 0, 0);
                c = __builtin_amdgcn_mfma_f32_16x16x32_bf16(ah[kk], bl, c, 0, 0, 0);
                c = __builtin_amdgcn_mfma_f32_16x16x32_bf16(ah[kk], bh, c, 0, 0, 0);
            }
            acc[cb] = c;
        }
    }

#pragma unroll
    for (int cb = 0; cb < 4; ++cb) {
#pragma unroll
        for (int r = 0; r < 4; ++r) {
            const int row = row0 + w * 16 + 4 * g + r;
            const int col = n0 + cb * 16 + ln;
            if (TRANSQ) {
                const int b = row >> 11, s = row & 2047;
                const int h = col >> 6, k = col & 63;
                out[((size_t)(b * HEADS + h) * SEQ + s) * KD + k] = acc[cb][r];
            } else {
                out[(size_t)row * EMB + col] = acc[cb][r];
            }
        }
    }
}

__global__ __launch_bounds__(256) void proj_fp32_kernel(const float* __restrict__ in,
                                                        const float* __restrict__ W,
                                                        float* __restrict__ out) {
    __shared__ float x_s[8][EMB];
    const int block_row = blockIdx.x * 8;

    const float4* in4 = (const float4*)(in + (size_t)block_row * EMB);
    float4* xs4 = (float4*)(&x_s[0][0]);
    for (int i = threadIdx.x; i < 8 * EMB / 4; i += 256) xs4[i] = in4[i];
    __syncthreads();

    const int n  = (threadIdx.x & 127) * 4;
    const int rg = threadIdx.x >> 7;

    float acc[4][4] = {};
    for (int e = 0; e < EMB; ++e) {
        const float4 w4 = *(const float4*)(W + (size_t)e * EMB + n);
#pragma unroll
        for (int rr = 0; rr < 4; ++rr) {
            const float xv = x_s[rg + rr * 2][e];
            acc[rr][0] += xv * w4.x;
            acc[rr][1] += xv * w4.y;
            acc[rr][2] += xv * w4.z;
            acc[rr][3] += xv * w4.w;
        }
    }
#pragma unroll
    for (int rr = 0; rr < 4; ++rr) {
        const int row = block_row + rg + rr * 2;
        float4 o;
        o.x = acc[rr][0]; o.y = acc[rr][1]; o.z = acc[rr][2]; o.w = acc[rr][3];
        *(float4*)(out + (size_t)row * EMB + n) = o;
    }
}

// ===========================================================================
extern "C" void kernel_launch(void* const* d_in, const int* in_sizes, int n_in,
                              void* d_out, int out_size, void* d_ws, size_t ws_size,
                              hipStream_t stream) {
    const float* x  = (const float*)d_in[0];
    const float* ks = (const float*)d_in[1];
    const float* vs = (const float*)d_in[2];
    const float* wq = (const float*)d_in[3];
    const float* wo = (const float*)d_in[4];
    float* out = (float*)d_out;

    const int M = BATCH * SEQ;  // 8192

    // ---- tier A layout (byte offsets) ----
    const size_t XIMG_OFF = 0;
    const size_t WQ_OFF   = 16777216;
    const size_t WO_OFF   = 17825792;
    const size_t KIMG_OFF = 18350080;
    const size_t VIMG_OFF = 35127296;
    const size_t QHI_OFF  = 43515904;
    const size_t QLO_OFF  = 51904512;
    const size_t CTX_OFF  = 60293120;
    const size_t TIER_A   = 68681728;

    if (ws_size >= TIER_A) {
        unsigned short* ximg  = (unsigned short*)((char*)d_ws + XIMG_OFF);
        unsigned short* wqimg = (unsigned short*)((char*)d_ws + WQ_OFF);
        unsigned short* woimg = (unsigned short*)((char*)d_ws + WO_OFF);
        unsigned short* kimg  = (unsigned short*)((char*)d_ws + KIMG_OFF);
        unsigned short* vimg  = (unsigned short*)((char*)d_ws + VIMG_OFF);
        unsigned short* qhi   = (unsigned short*)((char*)d_ws + QHI_OFF);
        unsigned short* qlo   = (unsigned short*)((char*)d_ws + QLO_OFF);
        unsigned short* ctx   = (unsigned short*)((char*)d_ws + CTX_OFF);

        prep_all_kernel<<<dim3(3200), dim3(256), 0, stream>>>(
            x, wq, wo, ks, vs, ximg, wqimg, woimg, kimg, vimg);
        proj_q_kernel<<<dim3(M / 64, HEADS), dim3(256), 0, stream>>>(ximg, wqimg, qhi, qlo);
        attn5_kernel<<<dim3(SEQ / 64, BATCH * HEADS), dim3(256), 0, stream>>>(
            qhi, qlo, kimg, vimg, ctx);
        proj_o_kernel<<<dim3(M / 64, EMB / 64), dim3(256), 0, stream>>>(ctx, woimg, out);
        return;
    }

    // ---- tier B: round-8 path ----
    const size_t QBYTES  = (size_t)BATCH * HEADS * SEQ * KD * 4;
    const size_t CBYTES  = (size_t)BATCH * SEQ * EMB * 4;
    const size_t KIBYTES = (size_t)BATCH * HEADS * SEQ * KD * 2 * 2;
    const size_t VIBYTES = (size_t)BATCH * HEADS * SEQ * KD * 2;

    float* Q = (float*)d_ws;
    const bool mid_ws  = ws_size >= QBYTES + CBYTES;
    const bool full_ws = ws_size >= QBYTES + CBYTES + KIBYTES + VIBYTES;
    float* ctxf = mid_ws ? (float*)((char*)d_ws + QBYTES) : out;
    unsigned short* kimg = (unsigned short*)((char*)d_ws + QBYTES + CBYTES);
    unsigned short* vimg = (unsigned short*)((char*)d_ws + QBYTES + CBYTES + KIBYTES);

    proj_mfma_kernel<1><<<dim3(M / 64, EMB / 64), dim3(256), 0, stream>>>(x, wq, Q);

    if (full_ws) {
        prep_k_kernel<<<dim3(BATCH * HEADS * 32), dim3(256), 0, stream>>>(ks, kimg);
        prep_v_kernel<<<dim3(BATCH * HEADS * 32), dim3(256), 0, stream>>>(vs, vimg);
        attn3_kernel<1><<<dim3(SEQ / 64, BATCH * HEADS), dim3(256), 0, stream>>>(
            Q, ks, vs, kimg, vimg, ctxf);
    } else {
        attn3_kernel<0><<<dim3(SEQ / 64, BATCH * HEADS), dim3(256), 0, stream>>>(
            Q, ks, vs, nullptr, nullptr, ctxf);
    }

    if (mid_ws) {
        proj_mfma_kernel<0><<<dim3(M / 64, EMB / 64), dim3(256), 0, stream>>>(ctxf, wo, out);
    } else {
        proj_fp32_kernel<<<dim3(M / 8), dim3(256), 0, stream>>>(ctxf, wo, out);
    }
}